// Round 11
// baseline (1078.164 us; speedup 1.0000x reference)
//
#include <hip/hip_runtime.h>

// AudioMamba forward. GEMMs = pre-split bf16 MFMA (hi/lo, 3 MFMAs,
// fp32-accurate), padded LDS. Fused: xproj+dtproj one kernel (dtr in LDS);
// fwd-scan + bwd-scan + gate one kernel (yfull in LDS, no ybuf).
// Inputs fp32, output fp32. B=4, L=256, DM=512, DI=1024, S=16, R=32, DEPTH=4.

#define BB 4
#define LL 256
#define DM 512
#define DI 1024
#define LDST 40   // LDS row stride in u16 (pad 32->40 kills bank conflicts)

typedef unsigned short u16;
typedef unsigned int u32;
typedef __attribute__((ext_vector_type(8))) short s8v;   // 8 bf16 (4 VGPRs)
typedef __attribute__((ext_vector_type(4))) float f4v;   // MFMA accumulator

__device__ __forceinline__ float silu_f(float x){ return x/(1.f+__expf(-x)); }
__device__ __forceinline__ float b2f(u16 u){
  union { u32 i; float f; } v; v.i = ((u32)u) << 16; return v.f;
}
__device__ __forceinline__ void b2x2(u32 w, float& lo, float& hi){
  union { u32 i; float f; } a, b;
  a.i = w << 16; b.i = w & 0xffff0000u;
  lo = a.f; hi = b.f;
}
__device__ __forceinline__ u16 f2bf(float f){
  union { float f; u32 u; } v; v.f = f;
  u32 r = (v.u + 0x7fffu + ((v.u >> 16) & 1u)) >> 16;
  return (u16)r;
}

// sum over 16-lane DPP row; full sum lands in lane 15 of each row (VALU-only)
__device__ __forceinline__ float row_sum16(float p){
  union { float f; int i; } v, r;
  v.f = p;
  r.i = __builtin_amdgcn_update_dpp(0, v.i, 0x111, 0xF, 0xF, true); v.f += r.f;
  r.i = __builtin_amdgcn_update_dpp(0, v.i, 0x112, 0xF, 0xF, true); v.f += r.f;
  r.i = __builtin_amdgcn_update_dpp(0, v.i, 0x114, 0xF, 0xF, true); v.f += r.f;
  r.i = __builtin_amdgcn_update_dpp(0, v.i, 0x118, 0xF, 0xF, true); v.f += r.f;
  return v.f;
}

__device__ __forceinline__ void block_reduce2(float& a, float& b, float* sc, int nw){
  int lane = threadIdx.x & 63, wid = threadIdx.x >> 6;
#pragma unroll
  for (int o = 32; o > 0; o >>= 1){
    a += __shfl_down(a, o, 64);
    b += __shfl_down(b, o, 64);
  }
  if (lane == 0){ sc[wid*2] = a; sc[wid*2+1] = b; }
  __syncthreads();
  float ta = 0.f, tb = 0.f;
  for (int i = 0; i < nw; ++i){ ta += sc[i*2]; tb += sc[i*2+1]; }
  a = ta; b = tb;
}

// ---- per-layer weight split: in_proj, out_proj, xproj(F,B), dtproj(F,B) ----
__global__ __launch_bounds__(256) void convert_w(const float* __restrict__ inW,
    const float* __restrict__ outW, const float* __restrict__ xwF,
    const float* __restrict__ xwB, const float* __restrict__ dtwF,
    const float* __restrict__ dtwB, u16* __restrict__ inHi, u16* __restrict__ inLo,
    u16* __restrict__ outHi, u16* __restrict__ outLo, u16* __restrict__ xwHi,
    u16* __restrict__ xwLo, u16* __restrict__ dtwHi, u16* __restrict__ dtwLo){
  int idx = blockIdx.x*256 + threadIdx.x;
  const float4* src; ushort4* dh; ushort4* dl;
  if (idx < 262144){
    src = (const float4*)inW + idx;
    dh = (ushort4*)inHi + idx; dl = (ushort4*)inLo + idx;
  } else if (idx < 393216){
    int j = idx - 262144;
    src = (const float4*)outW + j;
    dh = (ushort4*)outHi + j; dl = (ushort4*)outLo + j;
  } else if (idx < 409600){
    int j = idx - 393216;
    src = (const float4*)xwF + j;
    dh = (ushort4*)xwHi + j; dl = (ushort4*)xwLo + j;
  } else if (idx < 425984){
    int j = idx - 409600;
    src = (const float4*)xwB + j;
    dh = (ushort4*)(xwHi + 65536) + j; dl = (ushort4*)(xwLo + 65536) + j;
  } else if (idx < 434176){
    int j = idx - 425984;
    src = (const float4*)dtwF + j;
    dh = (ushort4*)dtwHi + j; dl = (ushort4*)dtwLo + j;
  } else {
    int j = idx - 434176;
    src = (const float4*)dtwB + j;
    dh = (ushort4*)(dtwHi + 32768) + j; dl = (ushort4*)(dtwLo + 32768) + j;
  }
  float4 v = *src;
  ushort4 h, l;
  h.x = f2bf(v.x); l.x = f2bf(v.x - b2f(h.x));
  h.y = f2bf(v.y); l.y = f2bf(v.y - b2f(h.y));
  h.z = f2bf(v.z); l.z = f2bf(v.z - b2f(h.z));
  h.w = f2bf(v.w); l.w = f2bf(v.w - b2f(h.w));
  *dh = h; *dl = l;
}

// ---- patch embed: 256 blocks (b4, ph8, pg4, dhalf2); 8 tokens per block ----
__global__ __launch_bounds__(256) void patch_embed(const float* __restrict__ x,
    const float* __restrict__ pw, const float* __restrict__ pb, float* __restrict__ h){
  __shared__ float xs[8*256];
  int blk = blockIdx.x;
  int b = blk >> 6, ph = (blk >> 3) & 7, pg = (blk >> 1) & 3, dh = blk & 1;
  int t = threadIdx.x;
  for (int idx = t; idx < 2048; idx += 256){
    int j = idx >> 8, pix = idx & 255, p = pix >> 4, q = pix & 15;
    xs[idx] = x[(size_t)(b*128 + ph*16 + p)*512 + pg*128 + j*16 + q];
  }
  __syncthreads();
  int d = dh*256 + t;
  float acc[8] = {};
  const float* wr = pw + (size_t)d*256;
  for (int i = 0; i < 256; i += 8){
    float4 w0 = *(const float4*)(wr + i);
    float4 w1 = *(const float4*)(wr + i + 4);
    float wf[8] = {w0.x,w0.y,w0.z,w0.w,w1.x,w1.y,w1.z,w1.w};
#pragma unroll
    for (int j = 0; j < 8; ++j){
#pragma unroll
      for (int jj = 0; jj < 8; ++jj)
        acc[j] = fmaf(xs[j*256 + i + jj], wf[jj], acc[j]);
    }
  }
  float bias = pb[d];
#pragma unroll
  for (int j = 0; j < 8; ++j)
    h[(size_t)(b*256 + ph*32 + pg*8 + j)*512 + d] = acc[j] + bias;
}

// ---- prep_ln: LN(h) -> bf16 hi/lo; one block per token row ----
__global__ __launch_bounds__(256) void prep_ln(const float* __restrict__ x,
    const float* __restrict__ w, const float* __restrict__ bias, int wOff,
    u16* __restrict__ hiO, u16* __restrict__ loO){
  __shared__ float sc[8];
  int row = blockIdx.x, t = threadIdx.x;
  const float* xr = x + (size_t)row*DM;
  float v0 = xr[t], v1 = xr[t + 256];
  float s = v0 + v1, ss = v0*v0 + v1*v1;
  block_reduce2(s, ss, sc, 4);
  float mean = s * (1.f/512.f);
  float var = ss * (1.f/512.f) - mean*mean;
  float inv = rsqrtf(var + 1e-5f);
  float o0 = (v0 - mean)*inv*w[wOff + t]       + bias[wOff + t];
  float o1 = (v1 - mean)*inv*w[wOff + t + 256] + bias[wOff + t + 256];
  u16 h0 = f2bf(o0), h1 = f2bf(o1);
  hiO[(size_t)row*DM + t]       = h0;
  hiO[(size_t)row*DM + t + 256] = h1;
  loO[(size_t)row*DM + t]       = f2bf(o0 - b2f(h0));
  loO[(size_t)row*DM + t + 256] = f2bf(o1 - b2f(h1));
}

// ---- generic pre-split-bf16 MFMA GEMM: C(M,N) (+)= A(M,K) @ B(N,K)^T ----
__global__ __launch_bounds__(256) void gemm_bf16(const u16* __restrict__ Ahi_g,
    const u16* __restrict__ Alo_g, int As, const u16* __restrict__ Bhi_g,
    const u16* __restrict__ Blo_g, int Bs, float* __restrict__ C, int Cs,
    int K, int addFlag){
  __shared__ __align__(16) u16 Ah[64*LDST], Al[64*LDST], Bh[64*LDST], Bl[64*LDST];
  int bm = blockIdx.y*64, bn = blockIdx.x*64;
  int t = threadIdx.x;
  int sr = t >> 2, sc8 = (t & 3)*8;
  int lane = t & 63, wv = t >> 6, ml = lane & 15, quad = lane >> 4;
  int mq = wv >> 1, nq = wv & 1;
  f4v acc[2][2] = {};
  for (int k0 = 0; k0 < K; k0 += 32){
    *(uint4*)&Ah[sr*LDST + sc8] = *(const uint4*)(Ahi_g + (size_t)(bm + sr)*As + k0 + sc8);
    *(uint4*)&Al[sr*LDST + sc8] = *(const uint4*)(Alo_g + (size_t)(bm + sr)*As + k0 + sc8);
    *(uint4*)&Bh[sr*LDST + sc8] = *(const uint4*)(Bhi_g + (size_t)(bn + sr)*Bs + k0 + sc8);
    *(uint4*)&Bl[sr*LDST + sc8] = *(const uint4*)(Blo_g + (size_t)(bn + sr)*Bs + k0 + sc8);
    __syncthreads();
    s8v ah[2], al2[2], bh2[2], bl2[2];
#pragma unroll
    for (int mt = 0; mt < 2; ++mt){
      int row = mq*32 + mt*16 + ml;
      ah[mt]  = *(s8v*)&Ah[row*LDST + quad*8];
      al2[mt] = *(s8v*)&Al[row*LDST + quad*8];
    }
#pragma unroll
    for (int nt = 0; nt < 2; ++nt){
      int col = nq*32 + nt*16 + ml;
      bh2[nt] = *(s8v*)&Bh[col*LDST + quad*8];
      bl2[nt] = *(s8v*)&Bl[col*LDST + quad*8];
    }
#pragma unroll
    for (int mt = 0; mt < 2; ++mt)
#pragma unroll
      for (int nt = 0; nt < 2; ++nt){
        acc[mt][nt] = __builtin_amdgcn_mfma_f32_16x16x32_bf16(ah[mt],  bh2[nt], acc[mt][nt], 0, 0, 0);
        acc[mt][nt] = __builtin_amdgcn_mfma_f32_16x16x32_bf16(al2[mt], bh2[nt], acc[mt][nt], 0, 0, 0);
        acc[mt][nt] = __builtin_amdgcn_mfma_f32_16x16x32_bf16(ah[mt],  bl2[nt], acc[mt][nt], 0, 0, 0);
      }
    __syncthreads();
  }
#pragma unroll
  for (int mt = 0; mt < 2; ++mt)
#pragma unroll
    for (int nt = 0; nt < 2; ++nt)
#pragma unroll
      for (int r = 0; r < 4; ++r){
        float* cp = C + (size_t)(bm + mq*32 + mt*16 + quad*4 + r)*Cs +
                    bn + nq*32 + nt*16 + ml;
        if (addFlag) *cp += acc[mt][nt][r];
        else         *cp  = acc[mt][nt][r];
      }
}

// ---- conv (K=4 causal depthwise) + SiLU -> u as bf16 hi/lo ----
__global__ __launch_bounds__(256) void conv_silu_split(const float* __restrict__ xz,
    const float* __restrict__ cwF, const float* __restrict__ cbF,
    const float* __restrict__ cwB, const float* __restrict__ cbB,
    int cwOff, int cbOff, u16* __restrict__ uHi, u16* __restrict__ uLo){
  int blk = blockIdx.x;
  int dir = blk >> 8, rem = blk & 255, b = rem >> 6, lg = rem & 63;
  int l0 = lg*4;
  const float* cw = dir ? cwB : cwF;
  const float* cb = dir ? cbB : cbF;
  int t = threadIdx.x;
  int rbase = (dir*BB + b)*LL;
  for (int dd = 0; dd < 4; ++dd){
    int d = t + dd*256;
    float4 w4 = *(const float4*)(cw + cwOff + d*4);
    float wf[4] = {w4.x, w4.y, w4.z, w4.w};
    float bias = cb[cbOff + d];
#pragma unroll
    for (int r = 0; r < 4; ++r){
      int l = l0 + r;
      float acc = bias;
#pragma unroll
      for (int k = 0; k < 4; ++k){
        int li = l + k - 3;
        if (li >= 0){
          int sl = dir ? (LL-1-li) : li;
          acc = fmaf(xz[(size_t)(b*LL + sl)*2048 + d], wf[k], acc);
        }
      }
      float uval = silu_f(acc);
      u16 h = f2bf(uval);
      uHi[(size_t)(rbase + l)*DI + d] = h;
      uLo[(size_t)(rbase + l)*DI + d] = f2bf(uval - b2f(h));
    }
  }
}

// ---- fused xproj + dtproj: per block 64 rows.
// xdbl(2048,64) = u @ xw^T ; dtr kept in LDS; dt(2048,1024) = softplus(dtr@dtw^T + b)
__global__ __launch_bounds__(256) void gemm_xproj_dt(const u16* __restrict__ uHi,
    const u16* __restrict__ uLo, const u16* __restrict__ xwHi,
    const u16* __restrict__ xwLo, const u16* __restrict__ dtwHi,
    const u16* __restrict__ dtwLo, const float* __restrict__ dtbF,
    const float* __restrict__ dtbB, int bOff,
    float* __restrict__ xdbl, float* __restrict__ dtOut){
  __shared__ __align__(16) u16 Ah[64*LDST], Al[64*LDST], Bh[64*LDST], Bl[64*LDST];
  __shared__ __align__(16) u16 DtrH[64*LDST], DtrL[64*LDST];
  int bm = blockIdx.y*64;
  int dir = bm >> 10;
  const u16* BhG = xwHi + dir*65536;
  const u16* BlG = xwLo + dir*65536;
  int t = threadIdx.x;
  int sr = t >> 2, sc8 = (t & 3)*8;
  int lane = t & 63, wv = t >> 6, ml = lane & 15, quad = lane >> 4;
  int mq = wv >> 1, nq = wv & 1;
  f4v acc[2][2] = {};
  for (int k0 = 0; k0 < 1024; k0 += 32){
    *(uint4*)&Ah[sr*LDST + sc8] = *(const uint4*)(uHi + (size_t)(bm + sr)*1024 + k0 + sc8);
    *(uint4*)&Al[sr*LDST + sc8] = *(const uint4*)(uLo + (size_t)(bm + sr)*1024 + k0 + sc8);
    *(uint4*)&Bh[sr*LDST + sc8] = *(const uint4*)(BhG + (size_t)sr*1024 + k0 + sc8);
    *(uint4*)&Bl[sr*LDST + sc8] = *(const uint4*)(BlG + (size_t)sr*1024 + k0 + sc8);
    __syncthreads();
    s8v ah[2], al2[2], bh2[2], bl2[2];
#pragma unroll
    for (int mt = 0; mt < 2; ++mt){
      int row = mq*32 + mt*16 + ml;
      ah[mt]  = *(s8v*)&Ah[row*LDST + quad*8];
      al2[mt] = *(s8v*)&Al[row*LDST + quad*8];
    }
#pragma unroll
    for (int nt = 0; nt < 2; ++nt){
      int col = nq*32 + nt*16 + ml;
      bh2[nt] = *(s8v*)&Bh[col*LDST + quad*8];
      bl2[nt] = *(s8v*)&Bl[col*LDST + quad*8];
    }
#pragma unroll
    for (int mt = 0; mt < 2; ++mt)
#pragma unroll
      for (int nt = 0; nt < 2; ++nt){
        acc[mt][nt] = __builtin_amdgcn_mfma_f32_16x16x32_bf16(ah[mt],  bh2[nt], acc[mt][nt], 0, 0, 0);
        acc[mt][nt] = __builtin_amdgcn_mfma_f32_16x16x32_bf16(al2[mt], bh2[nt], acc[mt][nt], 0, 0, 0);
        acc[mt][nt] = __builtin_amdgcn_mfma_f32_16x16x32_bf16(ah[mt],  bl2[nt], acc[mt][nt], 0, 0, 0);
      }
    __syncthreads();
  }
#pragma unroll
  for (int mt = 0; mt < 2; ++mt)
#pragma unroll
    for (int nt = 0; nt < 2; ++nt){
      int col = nq*32 + nt*16 + ml;
#pragma unroll
      for (int r = 0; r < 4; ++r){
        int lrow = mq*32 + mt*16 + quad*4 + r;
        float v = acc[mt][nt][r];
        xdbl[(size_t)(bm + lrow)*64 + col] = v;
        if (nq == 0){  // col < 32 : dt-rank slice -> LDS
          u16 h = f2bf(v);
          DtrH[lrow*LDST + col] = h;
          DtrL[lrow*LDST + col] = f2bf(v - b2f(h));
        }
      }
    }
  __syncthreads();
  // ---- dt GEMM: M=64 (this block's rows), N=1024, K=32 ----
  const u16* DhG = dtwHi + dir*32768;
  const u16* DlG = dtwLo + dir*32768;
  const float* dtb = dir ? dtbB : dtbF;
  for (int nt0 = 0; nt0 < 1024; nt0 += 64){
    *(uint4*)&Bh[sr*LDST + sc8] = *(const uint4*)(DhG + (size_t)(nt0 + sr)*32 + sc8);
    *(uint4*)&Bl[sr*LDST + sc8] = *(const uint4*)(DlG + (size_t)(nt0 + sr)*32 + sc8);
    __syncthreads();
    f4v acc2[2][2] = {};
    s8v ah[2], al2[2], bh2[2], bl2[2];
#pragma unroll
    for (int mt = 0; mt < 2; ++mt){
      int row = mq*32 + mt*16 + ml;
      ah[mt]  = *(s8v*)&DtrH[row*LDST + quad*8];
      al2[mt] = *(s8v*)&DtrL[row*LDST + quad*8];
    }
#pragma unroll
    for (int nt = 0; nt < 2; ++nt){
      int col = nq*32 + nt*16 + ml;
      bh2[nt] = *(s8v*)&Bh[col*LDST + quad*8];
      bl2[nt] = *(s8v*)&Bl[col*LDST + quad*8];
    }
#pragma unroll
    for (int mt = 0; mt < 2; ++mt)
#pragma unroll
      for (int nt = 0; nt < 2; ++nt){
        acc2[mt][nt] = __builtin_amdgcn_mfma_f32_16x16x32_bf16(ah[mt],  bh2[nt], acc2[mt][nt], 0, 0, 0);
        acc2[mt][nt] = __builtin_amdgcn_mfma_f32_16x16x32_bf16(al2[mt], bh2[nt], acc2[mt][nt], 0, 0, 0);
        acc2[mt][nt] = __builtin_amdgcn_mfma_f32_16x16x32_bf16(ah[mt],  bl2[nt], acc2[mt][nt], 0, 0, 0);
      }
#pragma unroll
    for (int mt = 0; mt < 2; ++mt)
#pragma unroll
      for (int nt = 0; nt < 2; ++nt){
        int gcol = nt0 + nq*32 + nt*16 + ml;
        float bias = dtb[bOff + gcol];
#pragma unroll
        for (int r = 0; r < 4; ++r){
          int grow = bm + mq*32 + mt*16 + quad*4 + r;
          float sv = acc2[mt][nt][r] + bias;
          dtOut[(size_t)grow*1024 + gcol] = (sv > 15.f) ? sv : log1pf(__expf(sv));
        }
      }
    __syncthreads();
  }
}

// ---- fused fwd scan + bwd scan + gate: block per (b, 16-d group); 256 blocks ----
__global__ __launch_bounds__(256) void scan_gate(const float* __restrict__ dt,
    const u16* __restrict__ uHi, const u16* __restrict__ uLo,
    const float* __restrict__ xd, const float* __restrict__ xz,
    const float* __restrict__ AlogF, const float* __restrict__ AlogB,
    const float* __restrict__ DF, const float* __restrict__ DB,
    int aOff, int dOff, u16* __restrict__ gHi, u16* __restrict__ gLo){
  __shared__ __align__(16) float dtuT[16][516];
  __shared__ __align__(16) float BCT[16][516];
  __shared__ __align__(16) float yfull[256][20];
  __shared__ __align__(16) float ybt[128][20];
  int blk = blockIdx.x;
  int b = blk >> 6, dg = blk & 63;
  int t = threadIdx.x;
  int s = t & 15, dl = t >> 4;
  float AvF = -__expf(AlogF[aOff + dg*256 + t]);
  float AvB = -__expf(AlogB[aOff + dg*256 + t]);
  float DpF = DF[dOff + dg*16 + dl];
  float DpB = DB[dOff + dg*16 + dl];
#pragma unroll
  for (int dirp = 0; dirp < 2; ++dirp){
    int rbase = (dirp*BB + b)*LL;
    // stage dt/u (transposed pairs) and B/C
    {
      int q = t & 3, lb = t >> 2;
      for (int pass = 0; pass < 4; ++pass){
        int l = pass*64 + lb;
        size_t base = (size_t)(rbase + l)*DI + dg*16 + q*4;
        float4 dv = *(const float4*)(dt + base);
        uint2 uh = *(const uint2*)(uHi + base);
        uint2 ul = *(const uint2*)(uLo + base);
        float h0,h1,h2,h3,l0f,l1f,l2f,l3f;
        b2x2(uh.x, h0, h1); b2x2(uh.y, h2, h3);
        b2x2(ul.x, l0f, l1f); b2x2(ul.y, l2f, l3f);
        float2 p0 = {dv.x, h0 + l0f}, p1 = {dv.y, h1 + l1f};
        float2 p2 = {dv.z, h2 + l2f}, p3 = {dv.w, h3 + l3f};
        *(float2*)&dtuT[q*4+0][l*2] = p0;
        *(float2*)&dtuT[q*4+1][l*2] = p1;
        *(float2*)&dtuT[q*4+2][l*2] = p2;
        *(float2*)&dtuT[q*4+3][l*2] = p3;
      }
      int h8 = t & 7, lb8 = t >> 3;
      for (int pass = 0; pass < 8; ++pass){
        int l = pass*32 + lb8;
        float4 v = *(const float4*)(xd + (size_t)(rbase + l)*64 + 32 + h8*4);
        if (h8 < 4){
          int s0 = h8*4;
          BCT[s0+0][l*2] = v.x; BCT[s0+1][l*2] = v.y;
          BCT[s0+2][l*2] = v.z; BCT[s0+3][l*2] = v.w;
        } else {
          int s0 = (h8-4)*4;
          BCT[s0+0][l*2+1] = v.x; BCT[s0+1][l*2+1] = v.y;
          BCT[s0+2][l*2+1] = v.z; BCT[s0+3][l*2+1] = v.w;
        }
      }
    }
    __syncthreads();
    float Av = dirp ? AvB : AvF;
    float Dp = dirp ? DpB : DpF;
    float h = 0.f;
    if (dirp == 0){
      // forward: write yfull[l][dl]
      for (int l0 = 0; l0 < 256; l0 += 4){
        float4 du01 = *(const float4*)&dtuT[dl][l0*2];
        float4 du23 = *(const float4*)&dtuT[dl][l0*2 + 4];
        float4 bc01 = *(const float4*)&BCT[s][l0*2];
        float4 bc23 = *(const float4*)&BCT[s][l0*2 + 4];
        float dtv[4] = {du01.x, du01.z, du23.x, du23.z};
        float uv[4]  = {du01.y, du01.w, du23.y, du23.w};
        float Bv[4]  = {bc01.x, bc01.z, bc23.x, bc23.z};
        float Cv[4]  = {bc01.y, bc01.w, bc23.y, bc23.w};
#pragma unroll
        for (int i = 0; i < 4; ++i){
          float a = __expf(dtv[i] * Av);
          h = fmaf(a, h, dtv[i]*uv[i]*Bv[i]);
          float sum = row_sum16(h * Cv[i]);
          if (s == 15) yfull[l0 + i][dl] = fmaf(uv[i], Dp, sum);
        }
      }
      __syncthreads();
    } else {
      // backward: ybt per half, then gate-combine with yfull and write g
      for (int half = 0; half < 2; ++half){
        for (int l0 = half*128; l0 < half*128 + 128; l0 += 4){
          float4 du01 = *(const float4*)&dtuT[dl][l0*2];
          float4 du23 = *(const float4*)&dtuT[dl][l0*2 + 4];
          float4 bc01 = *(const float4*)&BCT[s][l0*2];
          float4 bc23 = *(const float4*)&BCT[s][l0*2 + 4];
          float dtv[4] = {du01.x, du01.z, du23.x, du23.z};
          float uv[4]  = {du01.y, du01.w, du23.y, du23.w};
          float Bv[4]  = {bc01.x, bc01.z, bc23.x, bc23.z};
          float Cv[4]  = {bc01.y, bc01.w, bc23.y, bc23.w};
#pragma unroll
          for (int i = 0; i < 4; ++i){
            float a = __expf(dtv[i] * Av);
            h = fmaf(a, h, dtv[i]*uv[i]*Bv[i]);
            float sum = row_sum16(h * Cv[i]);
            if (s == 15) ybt[(l0 + i) & 127][dl] = fmaf(uv[i], Dp, sum);
          }
        }
        __syncthreads();
        {
          int d4 = t & 3, lh = t >> 2;
          for (int pass = 0; pass < 2; ++pass){
            int lr = pass*64 + lh;
            int lo = 255 - (half*128 + lr);
            float4 yf4 = *(float4*)&yfull[lo][d4*4];
            float4 yb4 = *(float4*)&ybt[lr][d4*4];
            float4 z4 = *(const float4*)(xz + (size_t)(b*256 + lo)*2048 + 1024 + dg*16 + d4*4);
            float g0 = (yf4.x + yb4.x)*silu_f(z4.x);
            float g1 = (yf4.y + yb4.y)*silu_f(z4.y);
            float g2 = (yf4.z + yb4.z)*silu_f(z4.z);
            float g3 = (yf4.w + yb4.w)*silu_f(z4.w);
            ushort4 hh, ll;
            hh.x = f2bf(g0); ll.x = f2bf(g0 - b2f(hh.x));
            hh.y = f2bf(g1); ll.y = f2bf(g1 - b2f(hh.y));
            hh.z = f2bf(g2); ll.z = f2bf(g2 - b2f(hh.z));
            hh.w = f2bf(g3); ll.w = f2bf(g3 - b2f(hh.w));
            size_t go = (size_t)(b*256 + lo)*1024 + dg*16 + d4*4;
            *(ushort4*)(gHi + go) = hh;
            *(ushort4*)(gLo + go) = ll;
          }
        }
        __syncthreads();
      }
    }
  }
}

// ---- final LayerNorm ----
__global__ __launch_bounds__(256) void ln_kernel(const float* __restrict__ x,
    const float* __restrict__ w, const float* __restrict__ bias,
    float* __restrict__ y){
  __shared__ float sc[8];
  int row = blockIdx.x, t = threadIdx.x;
  const float* xr = x + (size_t)row*DM;
  float v0 = xr[t], v1 = xr[t + 256];
  float s = v0 + v1, ss = v0*v0 + v1*v1;
  block_reduce2(s, ss, sc, 4);
  float mean = s * (1.f/512.f);
  float var = ss * (1.f/512.f) - mean*mean;
  float inv = rsqrtf(var + 1e-5f);
  float* yr = y + (size_t)row*DM;
  yr[t]       = (v0 - mean)*inv*w[t]       + bias[t];
  yr[t + 256] = (v1 - mean)*inv*w[t + 256] + bias[t + 256];
}

// ---- pool: mean over L, coalesced; 32 blocks (4 b x 8 d-groups) ----
__global__ __launch_bounds__(256) void pool_kernel(const float* __restrict__ hn,
    float* __restrict__ feat){
  __shared__ float part[4][64];
  int b = blockIdx.x >> 3, dg = blockIdx.x & 7;
  int t = threadIdx.x, dl = t & 63, lq = t >> 6;
  const float* p = hn + (size_t)(b*256 + lq*64)*512 + dg*64 + dl;
  float s = 0.f;
#pragma unroll 4
  for (int i = 0; i < 64; ++i) s += p[(size_t)i*512];
  part[lq][dl] = s;
  __syncthreads();
  if (t < 64)
    feat[b*512 + dg*64 + t] =
        (part[0][t] + part[1][t] + part[2][t] + part[3][t]) * (1.f/256.f);
}

// ---- head: LN + fc1/relu + fc2; 4 blocks ----
__global__ __launch_bounds__(512) void head_kernel(const float* __restrict__ feat,
    const float* __restrict__ lnw, const float* __restrict__ lnb,
    const float* __restrict__ fc1w, const float* __restrict__ fc1b,
    const float* __restrict__ fc2w, const float* __restrict__ fc2b,
    float* __restrict__ out){
  __shared__ float sc[16];
  __shared__ float cbuf[512];
  __shared__ float rbuf[512];
  int b = blockIdx.x, t = threadIdx.x;
  float v = feat[b*512 + t];
  float s = v, ss = v*v;
  block_reduce2(s, ss, sc, 8);
  float mean = s * (1.f/512.f);
  float var = ss * (1.f/512.f) - mean*mean;
  float inv = rsqrtf(var + 1e-5f);
  cbuf[t] = (v - mean)*inv*lnw[t] + lnb[t];
  __syncthreads();
  float a = fc1b[t];
  const float* w1 = fc1w + (size_t)t*512;
  for (int i = 0; i < 512; i += 8){
    float4 w0 = *(const float4*)(w1 + i);
    float4 w4 = *(const float4*)(w1 + i + 4);
    float wf[8] = {w0.x,w0.y,w0.z,w0.w,w4.x,w4.y,w4.z,w4.w};
#pragma unroll
    for (int j = 0; j < 8; ++j) a = fmaf(cbuf[i + j], wf[j], a);
  }
  rbuf[t] = fmaxf(a, 0.f);
  __syncthreads();
  if (t < 10){
    float a2 = fc2b[t];
    const float* w2 = fc2w + (size_t)t*512;
    for (int i = 0; i < 512; ++i) a2 = fmaf(rbuf[i], w2[i], a2);
    out[b*10 + t] = a2;
  }
}

extern "C" void kernel_launch(void* const* d_in, const int* in_sizes, int n_in,
                              void* d_out, int out_size, void* d_ws, size_t ws_size,
                              hipStream_t stream) {
  (void)in_sizes; (void)n_in; (void)out_size; (void)ws_size;
  const float* x          = (const float*)d_in[0];
  const float* patch_w    = (const float*)d_in[1];
  const float* patch_b    = (const float*)d_in[2];
  const float* in_proj_w  = (const float*)d_in[3];
  const float* conv_w_f   = (const float*)d_in[4];
  const float* conv_b_f   = (const float*)d_in[5];
  const float* xproj_w_f  = (const float*)d_in[6];
  const float* dtproj_w_f = (const float*)d_in[7];
  const float* dtproj_b_f = (const float*)d_in[8];
  const float* A_log_f    = (const float*)d_in[9];
  const float* D_f        = (const float*)d_in[10];
  const float* conv_w_b   = (const float*)d_in[11];
  const float* conv_b_b   = (const float*)d_in[12];
  const float* xproj_w_b  = (const float*)d_in[13];
  const float* dtproj_w_b = (const float*)d_in[14];
  const float* dtproj_b_b = (const float*)d_in[15];
  const float* A_log_b    = (const float*)d_in[16];
  const float* D_b        = (const float*)d_in[17];
  const float* out_proj_w = (const float*)d_in[18];
  const float* norm_w     = (const float*)d_in[19];
  const float* norm_b     = (const float*)d_in[20];
  const float* normf_w    = (const float*)d_in[21];
  const float* normf_b    = (const float*)d_in[22];
  const float* ln_w       = (const float*)d_in[23];
  const float* ln_b       = (const float*)d_in[24];
  const float* fc1_w      = (const float*)d_in[25];
  const float* fc1_b      = (const float*)d_in[26];
  const float* fc2_w      = (const float*)d_in[27];
  const float* fc2_b      = (const float*)d_in[28];

  float* ws   = (float*)d_ws;
  float* hbuf = ws;                       // [0, 524288)
  float* xz   = ws + 524288;              // [524288, 2621440)
  u16*   uHi  = (u16*)(ws + 2621440);     // 2097152 u16
  u16*   uLo  = (u16*)(ws + 3670016);     // 2097152 u16
  float* xdbl = ws + 4718592;             // 131072
  float* dtbuf= ws + 4849664;             // 2097152
  u16*   xwHi = (u16*)(ws + 6946816);     // 131072 u16
  u16*   xwLo = (u16*)(ws + 7012352);     // 131072 u16
  u16*   dtwHi= (u16*)(ws + 7077888);     // 65536 u16
  u16*   dtwLo= (u16*)(ws + 7110656);     // 65536 u16
  u16*   gHi  = (u16*)(ws + 7143424);     // 1048576 u16
  u16*   gLo  = (u16*)(ws + 7667712);     // 1048576 u16
  float* hn   = ws + 9043968;             // 524288 ; xnHi/xnLo alias
  u16*   inHi = (u16*)(ws + 9568256);
  u16*   inLo = (u16*)(ws + 10092544);
  u16*   outHi= (u16*)(ws + 10616832);
  u16*   outLo= (u16*)(ws + 10878976);
  float* feat = ws + 11141120;
  u16*   xnHi = (u16*)hn;
  u16*   xnLo = (u16*)(ws + 9306112);

  patch_embed<<<256, 256, 0, stream>>>(x, patch_w, patch_b, hbuf);
  for (int i = 0; i < 4; ++i){
    convert_w<<<1728, 256, 0, stream>>>(
        in_proj_w + (size_t)i*1048576, out_proj_w + (size_t)i*524288,
        xproj_w_f + (size_t)i*65536, xproj_w_b + (size_t)i*65536,
        dtproj_w_f + (size_t)i*32768, dtproj_w_b + (size_t)i*32768,
        inHi, inLo, outHi, outLo, xwHi, xwLo, dtwHi, dtwLo);
    prep_ln<<<1024, 256, 0, stream>>>(hbuf, norm_w, norm_b, i*512, xnHi, xnLo);
    gemm_bf16<<<dim3(32, 16), 256, 0, stream>>>(
        xnHi, xnLo, 512, inHi, inLo, 512, xz, 2048, 512, 0);
    conv_silu_split<<<512, 256, 0, stream>>>(
        xz, conv_w_f, conv_b_f, conv_w_b, conv_b_b, i*4096, i*1024, uHi, uLo);
    gemm_xproj_dt<<<dim3(1, 32), 256, 0, stream>>>(
        uHi, uLo, xwHi, xwLo, dtwHi, dtwLo, dtproj_b_f, dtproj_b_b, i*1024,
        xdbl, dtbuf);
    scan_gate<<<256, 256, 0, stream>>>(
        dtbuf, uHi, uLo, xdbl, xz, A_log_f, A_log_b, D_f, D_b,
        i*16384, i*1024, gHi, gLo);
    gemm_bf16<<<dim3(8, 16), 256, 0, stream>>>(
        gHi, gLo, 1024, outHi, outLo, 1024, hbuf, 512, 1024, 1);
  }
  ln_kernel<<<1024, 256, 0, stream>>>(hbuf, normf_w, normf_b, hn);
  pool_kernel<<<32, 256, 0, stream>>>(hn, feat);
  head_kernel<<<4, 512, 0, stream>>>(feat, ln_w, ln_b, fc1_w, fc1_b, fc2_w, fc2_b,
                                     (float*)d_out);
}

// Round 12
// 652.538 us; speedup vs baseline: 1.6523x; 1.6523x over previous
//
#include <hip/hip_runtime.h>

// AudioMamba forward. GEMMs = pre-split bf16 MFMA (hi/lo, 3 MFMAs,
// fp32-accurate), padded LDS. xproj = split-K (4 chunks, atomicAdd fp32).
// Inputs fp32, output fp32. B=4, L=256, DM=512, DI=1024, S=16, R=32, DEPTH=4.

#define BB 4
#define LL 256
#define DM 512
#define DI 1024
#define LDST 40   // LDS row stride in u16 (pad 32->40 kills bank conflicts)

typedef unsigned short u16;
typedef unsigned int u32;
typedef __attribute__((ext_vector_type(8))) short s8v;   // 8 bf16 (4 VGPRs)
typedef __attribute__((ext_vector_type(4))) float f4v;   // MFMA accumulator

__device__ __forceinline__ float silu_f(float x){ return x/(1.f+__expf(-x)); }
__device__ __forceinline__ float b2f(u16 u){
  union { u32 i; float f; } v; v.i = ((u32)u) << 16; return v.f;
}
__device__ __forceinline__ void b2x2(u32 w, float& lo, float& hi){
  union { u32 i; float f; } a, b;
  a.i = w << 16; b.i = w & 0xffff0000u;
  lo = a.f; hi = b.f;
}
__device__ __forceinline__ u16 f2bf(float f){
  union { float f; u32 u; } v; v.f = f;
  u32 r = (v.u + 0x7fffu + ((v.u >> 16) & 1u)) >> 16;
  return (u16)r;
}
__device__ __forceinline__ void split8(const float* f, s8v& hi, s8v& lo){
#pragma unroll
  for (int j = 0; j < 8; ++j){
    u16 h = f2bf(f[j]);
    float hf = b2f(h);
    hi[j] = (short)h;
    lo[j] = (short)f2bf(f[j] - hf);
  }
}

// sum over 16-lane DPP row; full sum lands in lane 15 of each row (VALU-only)
__device__ __forceinline__ float row_sum16(float p){
  union { float f; int i; } v, r;
  v.f = p;
  r.i = __builtin_amdgcn_update_dpp(0, v.i, 0x111, 0xF, 0xF, true); v.f += r.f;
  r.i = __builtin_amdgcn_update_dpp(0, v.i, 0x112, 0xF, 0xF, true); v.f += r.f;
  r.i = __builtin_amdgcn_update_dpp(0, v.i, 0x114, 0xF, 0xF, true); v.f += r.f;
  r.i = __builtin_amdgcn_update_dpp(0, v.i, 0x118, 0xF, 0xF, true); v.f += r.f;
  return v.f;
}

__device__ __forceinline__ void block_reduce2(float& a, float& b, float* sc, int nw){
  int lane = threadIdx.x & 63, wid = threadIdx.x >> 6;
#pragma unroll
  for (int o = 32; o > 0; o >>= 1){
    a += __shfl_down(a, o, 64);
    b += __shfl_down(b, o, 64);
  }
  if (lane == 0){ sc[wid*2] = a; sc[wid*2+1] = b; }
  __syncthreads();
  float ta = 0.f, tb = 0.f;
  for (int i = 0; i < nw; ++i){ ta += sc[i*2]; tb += sc[i*2+1]; }
  a = ta; b = tb;
}

// ---- per-layer weight split: in_proj, out_proj, xproj(F,B), dtproj(F,B) ----
__global__ __launch_bounds__(256) void convert_w(const float* __restrict__ inW,
    const float* __restrict__ outW, const float* __restrict__ xwF,
    const float* __restrict__ xwB, const float* __restrict__ dtwF,
    const float* __restrict__ dtwB, u16* __restrict__ inHi, u16* __restrict__ inLo,
    u16* __restrict__ outHi, u16* __restrict__ outLo, u16* __restrict__ xwHi,
    u16* __restrict__ xwLo, u16* __restrict__ dtwHi, u16* __restrict__ dtwLo){
  int idx = blockIdx.x*256 + threadIdx.x;
  const float4* src; ushort4* dh; ushort4* dl;
  if (idx < 262144){
    src = (const float4*)inW + idx;
    dh = (ushort4*)inHi + idx; dl = (ushort4*)inLo + idx;
  } else if (idx < 393216){
    int j = idx - 262144;
    src = (const float4*)outW + j;
    dh = (ushort4*)outHi + j; dl = (ushort4*)outLo + j;
  } else if (idx < 409600){
    int j = idx - 393216;
    src = (const float4*)xwF + j;
    dh = (ushort4*)xwHi + j; dl = (ushort4*)xwLo + j;
  } else if (idx < 425984){
    int j = idx - 409600;
    src = (const float4*)xwB + j;
    dh = (ushort4*)(xwHi + 65536) + j; dl = (ushort4*)(xwLo + 65536) + j;
  } else if (idx < 434176){
    int j = idx - 425984;
    src = (const float4*)dtwF + j;
    dh = (ushort4*)dtwHi + j; dl = (ushort4*)dtwLo + j;
  } else {
    int j = idx - 434176;
    src = (const float4*)dtwB + j;
    dh = (ushort4*)(dtwHi + 32768) + j; dl = (ushort4*)(dtwLo + 32768) + j;
  }
  float4 v = *src;
  ushort4 h, l;
  h.x = f2bf(v.x); l.x = f2bf(v.x - b2f(h.x));
  h.y = f2bf(v.y); l.y = f2bf(v.y - b2f(h.y));
  h.z = f2bf(v.z); l.z = f2bf(v.z - b2f(h.z));
  h.w = f2bf(v.w); l.w = f2bf(v.w - b2f(h.w));
  *dh = h; *dl = l;
}

// ---- patch embed: 256 blocks (b4, ph8, pg4, dhalf2); 8 tokens per block ----
__global__ __launch_bounds__(256) void patch_embed(const float* __restrict__ x,
    const float* __restrict__ pw, const float* __restrict__ pb, float* __restrict__ h){
  __shared__ float xs[8*256];
  int blk = blockIdx.x;
  int b = blk >> 6, ph = (blk >> 3) & 7, pg = (blk >> 1) & 3, dh = blk & 1;
  int t = threadIdx.x;
  for (int idx = t; idx < 2048; idx += 256){
    int j = idx >> 8, pix = idx & 255, p = pix >> 4, q = pix & 15;
    xs[idx] = x[(size_t)(b*128 + ph*16 + p)*512 + pg*128 + j*16 + q];
  }
  __syncthreads();
  int d = dh*256 + t;
  float acc[8] = {};
  const float* wr = pw + (size_t)d*256;
  for (int i = 0; i < 256; i += 8){
    float4 w0 = *(const float4*)(wr + i);
    float4 w1 = *(const float4*)(wr + i + 4);
    float wf[8] = {w0.x,w0.y,w0.z,w0.w,w1.x,w1.y,w1.z,w1.w};
#pragma unroll
    for (int j = 0; j < 8; ++j){
#pragma unroll
      for (int jj = 0; jj < 8; ++jj)
        acc[j] = fmaf(xs[j*256 + i + jj], wf[jj], acc[j]);
    }
  }
  float bias = pb[d];
#pragma unroll
  for (int j = 0; j < 8; ++j)
    h[(size_t)(b*256 + ph*32 + pg*8 + j)*512 + d] = acc[j] + bias;
}

// ---- prep_ln: LN(h) -> bf16 hi/lo; one block per token row ----
__global__ __launch_bounds__(256) void prep_ln(const float* __restrict__ x,
    const float* __restrict__ w, const float* __restrict__ bias, int wOff,
    u16* __restrict__ hiO, u16* __restrict__ loO){
  __shared__ float sc[8];
  int row = blockIdx.x, t = threadIdx.x;
  const float* xr = x + (size_t)row*DM;
  float v0 = xr[t], v1 = xr[t + 256];
  float s = v0 + v1, ss = v0*v0 + v1*v1;
  block_reduce2(s, ss, sc, 4);
  float mean = s * (1.f/512.f);
  float var = ss * (1.f/512.f) - mean*mean;
  float inv = rsqrtf(var + 1e-5f);
  float o0 = (v0 - mean)*inv*w[wOff + t]       + bias[wOff + t];
  float o1 = (v1 - mean)*inv*w[wOff + t + 256] + bias[wOff + t + 256];
  u16 h0 = f2bf(o0), h1 = f2bf(o1);
  hiO[(size_t)row*DM + t]       = h0;
  hiO[(size_t)row*DM + t + 256] = h1;
  loO[(size_t)row*DM + t]       = f2bf(o0 - b2f(h0));
  loO[(size_t)row*DM + t + 256] = f2bf(o1 - b2f(h1));
}

// ---- prep_gate: g = (yf+yb)*silu(z) -> bf16 hi/lo; one block per row ----
__global__ __launch_bounds__(256) void prep_gate(const float* __restrict__ ybuf,
    const float* __restrict__ xz, u16* __restrict__ gHi, u16* __restrict__ gLo){
  int row = blockIdx.x, t = threadIdx.x;
  int c = t*4;
  float4 yf = *(const float4*)(ybuf + (size_t)row*DI + c);
  float4 yb = *(const float4*)(ybuf + 1048576 + (size_t)row*DI + c);
  float4 zv = *(const float4*)(xz + (size_t)row*2048 + 1024 + c);
  float g0 = (yf.x + yb.x)*silu_f(zv.x);
  float g1 = (yf.y + yb.y)*silu_f(zv.y);
  float g2 = (yf.z + yb.z)*silu_f(zv.z);
  float g3 = (yf.w + yb.w)*silu_f(zv.w);
  ushort4 h, l;
  h.x = f2bf(g0); l.x = f2bf(g0 - b2f(h.x));
  h.y = f2bf(g1); l.y = f2bf(g1 - b2f(h.y));
  h.z = f2bf(g2); l.z = f2bf(g2 - b2f(h.z));
  h.w = f2bf(g3); l.w = f2bf(g3 - b2f(h.w));
  *(ushort4*)(gHi + (size_t)row*DI + c) = h;
  *(ushort4*)(gLo + (size_t)row*DI + c) = l;
}

// ---- generic pre-split-bf16 MFMA GEMM: C(M,N) (+)= A(M,K) @ B(N,K)^T ----
__global__ __launch_bounds__(256) void gemm_bf16(const u16* __restrict__ Ahi_g,
    const u16* __restrict__ Alo_g, int As, const u16* __restrict__ Bhi_g,
    const u16* __restrict__ Blo_g, int Bs, float* __restrict__ C, int Cs,
    int K, int addFlag){
  __shared__ __align__(16) u16 Ah[64*LDST], Al[64*LDST], Bh[64*LDST], Bl[64*LDST];
  int bm = blockIdx.y*64, bn = blockIdx.x*64;
  int t = threadIdx.x;
  int sr = t >> 2, sc8 = (t & 3)*8;
  int lane = t & 63, wv = t >> 6, ml = lane & 15, quad = lane >> 4;
  int mq = wv >> 1, nq = wv & 1;
  f4v acc[2][2] = {};
  for (int k0 = 0; k0 < K; k0 += 32){
    *(uint4*)&Ah[sr*LDST + sc8] = *(const uint4*)(Ahi_g + (size_t)(bm + sr)*As + k0 + sc8);
    *(uint4*)&Al[sr*LDST + sc8] = *(const uint4*)(Alo_g + (size_t)(bm + sr)*As + k0 + sc8);
    *(uint4*)&Bh[sr*LDST + sc8] = *(const uint4*)(Bhi_g + (size_t)(bn + sr)*Bs + k0 + sc8);
    *(uint4*)&Bl[sr*LDST + sc8] = *(const uint4*)(Blo_g + (size_t)(bn + sr)*Bs + k0 + sc8);
    __syncthreads();
    s8v ah[2], al2[2], bh2[2], bl2[2];
#pragma unroll
    for (int mt = 0; mt < 2; ++mt){
      int row = mq*32 + mt*16 + ml;
      ah[mt]  = *(s8v*)&Ah[row*LDST + quad*8];
      al2[mt] = *(s8v*)&Al[row*LDST + quad*8];
    }
#pragma unroll
    for (int nt = 0; nt < 2; ++nt){
      int col = nq*32 + nt*16 + ml;
      bh2[nt] = *(s8v*)&Bh[col*LDST + quad*8];
      bl2[nt] = *(s8v*)&Bl[col*LDST + quad*8];
    }
#pragma unroll
    for (int mt = 0; mt < 2; ++mt)
#pragma unroll
      for (int nt = 0; nt < 2; ++nt){
        acc[mt][nt] = __builtin_amdgcn_mfma_f32_16x16x32_bf16(ah[mt],  bh2[nt], acc[mt][nt], 0, 0, 0);
        acc[mt][nt] = __builtin_amdgcn_mfma_f32_16x16x32_bf16(al2[mt], bh2[nt], acc[mt][nt], 0, 0, 0);
        acc[mt][nt] = __builtin_amdgcn_mfma_f32_16x16x32_bf16(ah[mt],  bl2[nt], acc[mt][nt], 0, 0, 0);
      }
    __syncthreads();
  }
#pragma unroll
  for (int mt = 0; mt < 2; ++mt)
#pragma unroll
    for (int nt = 0; nt < 2; ++nt)
#pragma unroll
      for (int r = 0; r < 4; ++r){
        float* cp = C + (size_t)(bm + mq*32 + mt*16 + quad*4 + r)*Cs +
                    bn + nq*32 + nt*16 + ml;
        if (addFlag) *cp += acc[mt][nt][r];
        else         *cp  = acc[mt][nt][r];
      }
}

// ---- conv (K=4 causal depthwise) + SiLU -> u as bf16 hi/lo ----
__global__ __launch_bounds__(256) void conv_silu_split(const float* __restrict__ xz,
    const float* __restrict__ cwF, const float* __restrict__ cbF,
    const float* __restrict__ cwB, const float* __restrict__ cbB,
    int cwOff, int cbOff, u16* __restrict__ uHi, u16* __restrict__ uLo){
  int blk = blockIdx.x;
  int dir = blk >> 8, rem = blk & 255, b = rem >> 6, lg = rem & 63;
  int l0 = lg*4;
  const float* cw = dir ? cwB : cwF;
  const float* cb = dir ? cbB : cbF;
  int t = threadIdx.x;
  int rbase = (dir*BB + b)*LL;
  for (int dd = 0; dd < 4; ++dd){
    int d = t + dd*256;
    float4 w4 = *(const float4*)(cw + cwOff + d*4);
    float wf[4] = {w4.x, w4.y, w4.z, w4.w};
    float bias = cb[cbOff + d];
#pragma unroll
    for (int r = 0; r < 4; ++r){
      int l = l0 + r;
      float acc = bias;
#pragma unroll
      for (int k = 0; k < 4; ++k){
        int li = l + k - 3;
        if (li >= 0){
          int sl = dir ? (LL-1-li) : li;
          acc = fmaf(xz[(size_t)(b*LL + sl)*2048 + d], wf[k], acc);
        }
      }
      float uval = silu_f(acc);
      u16 h = f2bf(uval);
      uHi[(size_t)(rbase + l)*DI + d] = h;
      uLo[(size_t)(rbase + l)*DI + d] = f2bf(uval - b2f(h));
    }
  }
}

// ---- xproj split-K: xdbl(2048,64) += u(2048,1024)@xw(64,1024)^T over k-chunk ----
// grid (4 kchunks, 32 mtiles) = 128 blocks; fp32 atomicAdd into zeroed xdbl.
__global__ __launch_bounds__(256) void gemm_xproj_splitk(const u16* __restrict__ uHi,
    const u16* __restrict__ uLo, const u16* __restrict__ xwHi,
    const u16* __restrict__ xwLo, float* __restrict__ xdbl){
  __shared__ __align__(16) u16 Ah[64*LDST], Al[64*LDST], Bh[64*LDST], Bl[64*LDST];
  int bm = blockIdx.y*64;
  int kc = blockIdx.x;
  int dir = bm >> 10;
  const u16* BhG = xwHi + dir*65536;
  const u16* BlG = xwLo + dir*65536;
  int t = threadIdx.x;
  int sr = t >> 2, sc8 = (t & 3)*8;
  int lane = t & 63, wv = t >> 6, ml = lane & 15, quad = lane >> 4;
  int mq = wv >> 1, nq = wv & 1;
  f4v acc[2][2] = {};
  for (int k0 = kc*256; k0 < kc*256 + 256; k0 += 32){
    *(uint4*)&Ah[sr*LDST + sc8] = *(const uint4*)(uHi + (size_t)(bm + sr)*1024 + k0 + sc8);
    *(uint4*)&Al[sr*LDST + sc8] = *(const uint4*)(uLo + (size_t)(bm + sr)*1024 + k0 + sc8);
    *(uint4*)&Bh[sr*LDST + sc8] = *(const uint4*)(BhG + (size_t)sr*1024 + k0 + sc8);
    *(uint4*)&Bl[sr*LDST + sc8] = *(const uint4*)(BlG + (size_t)sr*1024 + k0 + sc8);
    __syncthreads();
    s8v ah[2], al2[2], bh2[2], bl2[2];
#pragma unroll
    for (int mt = 0; mt < 2; ++mt){
      int row = mq*32 + mt*16 + ml;
      ah[mt]  = *(s8v*)&Ah[row*LDST + quad*8];
      al2[mt] = *(s8v*)&Al[row*LDST + quad*8];
    }
#pragma unroll
    for (int nt = 0; nt < 2; ++nt){
      int col = nq*32 + nt*16 + ml;
      bh2[nt] = *(s8v*)&Bh[col*LDST + quad*8];
      bl2[nt] = *(s8v*)&Bl[col*LDST + quad*8];
    }
#pragma unroll
    for (int mt = 0; mt < 2; ++mt)
#pragma unroll
      for (int nt = 0; nt < 2; ++nt){
        acc[mt][nt] = __builtin_amdgcn_mfma_f32_16x16x32_bf16(ah[mt],  bh2[nt], acc[mt][nt], 0, 0, 0);
        acc[mt][nt] = __builtin_amdgcn_mfma_f32_16x16x32_bf16(al2[mt], bh2[nt], acc[mt][nt], 0, 0, 0);
        acc[mt][nt] = __builtin_amdgcn_mfma_f32_16x16x32_bf16(ah[mt],  bl2[nt], acc[mt][nt], 0, 0, 0);
      }
    __syncthreads();
  }
#pragma unroll
  for (int mt = 0; mt < 2; ++mt)
#pragma unroll
    for (int nt = 0; nt < 2; ++nt)
#pragma unroll
      for (int r = 0; r < 4; ++r)
        atomicAdd(xdbl + (size_t)(bm + mq*32 + mt*16 + quad*4 + r)*64 +
                  nq*32 + nt*16 + ml, acc[mt][nt][r]);
}

// ---- dt GEMM: dt(2048,1024) = softplus(xdbl[:, :32] @ dtw(1024,32)^T + b) ----
// A staged from fp32 xdbl (split inline). grid (16,32) = 512 blocks.
__global__ __launch_bounds__(256) void gemm_dt(const float* __restrict__ xdbl,
    const u16* __restrict__ dtwHi, const u16* __restrict__ dtwLo,
    const float* __restrict__ dtbF, const float* __restrict__ dtbB, int bOff,
    float* __restrict__ dtOut){
  __shared__ __align__(16) u16 Ah[64*LDST], Al[64*LDST], Bh[64*LDST], Bl[64*LDST];
  int bm = blockIdx.y*64, bn = blockIdx.x*64;
  int dir = bm >> 10;
  const u16* BhG = dtwHi + dir*32768;
  const u16* BlG = dtwLo + dir*32768;
  const float* dtb = dir ? dtbB : dtbF;
  int t = threadIdx.x;
  int sr = t >> 2, sc8 = (t & 3)*8;  // sc8 in {0,8,16,24}: exactly K=32
  int lane = t & 63, wv = t >> 6, ml = lane & 15, quad = lane >> 4;
  int mq = wv >> 1, nq = wv & 1;
  {
    const float* ap = xdbl + (size_t)(bm + sr)*64 + sc8;
    float4 a0 = *(const float4*)ap;
    float4 a1 = *(const float4*)(ap + 4);
    float af[8] = {a0.x,a0.y,a0.z,a0.w,a1.x,a1.y,a1.z,a1.w};
    s8v hi, lo; split8(af, hi, lo);
    *(s8v*)&Ah[sr*LDST + sc8] = hi;
    *(s8v*)&Al[sr*LDST + sc8] = lo;
  }
  *(uint4*)&Bh[sr*LDST + sc8] = *(const uint4*)(BhG + (size_t)(bn + sr)*32 + sc8);
  *(uint4*)&Bl[sr*LDST + sc8] = *(const uint4*)(BlG + (size_t)(bn + sr)*32 + sc8);
  __syncthreads();
  f4v acc[2][2] = {};
  s8v ah[2], al2[2], bh2[2], bl2[2];
#pragma unroll
  for (int mt = 0; mt < 2; ++mt){
    int row = mq*32 + mt*16 + ml;
    ah[mt]  = *(s8v*)&Ah[row*LDST + quad*8];
    al2[mt] = *(s8v*)&Al[row*LDST + quad*8];
  }
#pragma unroll
  for (int nt = 0; nt < 2; ++nt){
    int col = nq*32 + nt*16 + ml;
    bh2[nt] = *(s8v*)&Bh[col*LDST + quad*8];
    bl2[nt] = *(s8v*)&Bl[col*LDST + quad*8];
  }
#pragma unroll
  for (int mt = 0; mt < 2; ++mt)
#pragma unroll
    for (int nt = 0; nt < 2; ++nt){
      acc[mt][nt] = __builtin_amdgcn_mfma_f32_16x16x32_bf16(ah[mt],  bh2[nt], acc[mt][nt], 0, 0, 0);
      acc[mt][nt] = __builtin_amdgcn_mfma_f32_16x16x32_bf16(al2[mt], bh2[nt], acc[mt][nt], 0, 0, 0);
      acc[mt][nt] = __builtin_amdgcn_mfma_f32_16x16x32_bf16(ah[mt],  bl2[nt], acc[mt][nt], 0, 0, 0);
    }
#pragma unroll
  for (int mt = 0; mt < 2; ++mt)
#pragma unroll
    for (int nt = 0; nt < 2; ++nt){
      int col = bn + nq*32 + nt*16 + ml;
      float bias = dtb[bOff + col];
#pragma unroll
      for (int r = 0; r < 4; ++r){
        int row = bm + mq*32 + mt*16 + quad*4 + r;
        float sv = acc[mt][nt][r] + bias;
        dtOut[(size_t)row*1024 + col] = (sv > 15.f) ? sv : log1pf(__expf(sv));
      }
    }
}

// ---- coalesced LDS-tiled selective scan (u reconstructed from bf16 hi/lo) ----
__global__ __launch_bounds__(256) void scan_coal(const float* __restrict__ dt,
    const u16* __restrict__ uHi, const u16* __restrict__ uLo,
    const float* __restrict__ xd,
    const float* __restrict__ AlogF, const float* __restrict__ AlogB,
    const float* __restrict__ DF, const float* __restrict__ DB,
    int aOff, int dOff, float* __restrict__ y){
  __shared__ __align__(16) float dtuT[16][516];
  __shared__ __align__(16) float BCT[16][516];
  __shared__ __align__(16) float ytile[128][16];
  int blk = blockIdx.x;
  int dir = blk >> 8, b = (blk >> 6) & 3, dg = blk & 63;
  int t = threadIdx.x;
  int rbase = (dir*BB + b)*LL;
  const float* Alog = dir ? AlogB : AlogF;
  const float* Dpt  = dir ? DB : DF;
  {
    int q = t & 3, lb = t >> 2;
    for (int pass = 0; pass < 4; ++pass){
      int l = pass*64 + lb;
      size_t base = (size_t)(rbase + l)*DI + dg*16 + q*4;
      float4 dv = *(const float4*)(dt + base);
      uint2 uh = *(const uint2*)(uHi + base);
      uint2 ul = *(const uint2*)(uLo + base);
      float h0,h1,h2,h3,l0f,l1f,l2f,l3f;
      b2x2(uh.x, h0, h1); b2x2(uh.y, h2, h3);
      b2x2(ul.x, l0f, l1f); b2x2(ul.y, l2f, l3f);
      float2 p0 = {dv.x, h0 + l0f}, p1 = {dv.y, h1 + l1f};
      float2 p2 = {dv.z, h2 + l2f}, p3 = {dv.w, h3 + l3f};
      *(float2*)&dtuT[q*4+0][l*2] = p0;
      *(float2*)&dtuT[q*4+1][l*2] = p1;
      *(float2*)&dtuT[q*4+2][l*2] = p2;
      *(float2*)&dtuT[q*4+3][l*2] = p3;
    }
  }
  {
    int h8 = t & 7, lb = t >> 3;
    for (int pass = 0; pass < 8; ++pass){
      int l = pass*32 + lb;
      float4 v = *(const float4*)(xd + (size_t)(rbase + l)*64 + 32 + h8*4);
      if (h8 < 4){
        int s0 = h8*4;
        BCT[s0+0][l*2] = v.x; BCT[s0+1][l*2] = v.y;
        BCT[s0+2][l*2] = v.z; BCT[s0+3][l*2] = v.w;
      } else {
        int s0 = (h8-4)*4;
        BCT[s0+0][l*2+1] = v.x; BCT[s0+1][l*2+1] = v.y;
        BCT[s0+2][l*2+1] = v.z; BCT[s0+3][l*2+1] = v.w;
      }
    }
  }
  int s = t & 15, dl = t >> 4;
  float Av = -__expf(Alog[aOff + dg*256 + t]);
  float Dp = Dpt[dOff + dg*16 + dl];
  __syncthreads();
  float h = 0.f;
  for (int half = 0; half < 2; ++half){
    for (int l0 = half*128; l0 < half*128 + 128; l0 += 4){
      float4 du01 = *(const float4*)&dtuT[dl][l0*2];
      float4 du23 = *(const float4*)&dtuT[dl][l0*2 + 4];
      float4 bc01 = *(const float4*)&BCT[s][l0*2];
      float4 bc23 = *(const float4*)&BCT[s][l0*2 + 4];
      float dtv[4] = {du01.x, du01.z, du23.x, du23.z};
      float uv[4]  = {du01.y, du01.w, du23.y, du23.w};
      float Bv[4]  = {bc01.x, bc01.z, bc23.x, bc23.z};
      float Cv[4]  = {bc01.y, bc01.w, bc23.y, bc23.w};
#pragma unroll
      for (int i = 0; i < 4; ++i){
        float a = __expf(dtv[i] * Av);
        h = fmaf(a, h, dtv[i]*uv[i]*Bv[i]);
        float p = h * Cv[i];
        float sum = row_sum16(p);
        if (s == 15){
          int lr = (l0 + i) & 127;
          ytile[lr][dl] = fmaf(uv[i], Dp, sum);
        }
      }
    }
    __syncthreads();
    {
      int d4 = t & 3, lh = t >> 2;
      for (int pass = 0; pass < 2; ++pass){
        int lr = pass*64 + lh;
        int l = half*128 + lr;
        int lo = dir ? (255 - l) : l;
        float4 vv = *(const float4*)&ytile[lr][d4*4];
        *(float4*)(y + (size_t)(rbase + lo)*DI + dg*16 + d4*4) = vv;
      }
    }
    __syncthreads();
  }
}

// ---- final LayerNorm ----
__global__ __launch_bounds__(256) void ln_kernel(const float* __restrict__ x,
    const float* __restrict__ w, const float* __restrict__ bias,
    float* __restrict__ y){
  __shared__ float sc[8];
  int row = blockIdx.x, t = threadIdx.x;
  const float* xr = x + (size_t)row*DM;
  float v0 = xr[t], v1 = xr[t + 256];
  float s = v0 + v1, ss = v0*v0 + v1*v1;
  block_reduce2(s, ss, sc, 4);
  float mean = s * (1.f/512.f);
  float var = ss * (1.f/512.f) - mean*mean;
  float inv = rsqrtf(var + 1e-5f);
  float* yr = y + (size_t)row*DM;
  yr[t]       = (v0 - mean)*inv*w[t]       + bias[t];
  yr[t + 256] = (v1 - mean)*inv*w[t + 256] + bias[t + 256];
}

// ---- pool: mean over L, coalesced; 32 blocks (4 b x 8 d-groups) ----
__global__ __launch_bounds__(256) void pool_kernel(const float* __restrict__ hn,
    float* __restrict__ feat){
  __shared__ float part[4][64];
  int b = blockIdx.x >> 3, dg = blockIdx.x & 7;
  int t = threadIdx.x, dl = t & 63, lq = t >> 6;
  const float* p = hn + (size_t)(b*256 + lq*64)*512 + dg*64 + dl;
  float s = 0.f;
#pragma unroll 4
  for (int i = 0; i < 64; ++i) s += p[(size_t)i*512];
  part[lq][dl] = s;
  __syncthreads();
  if (t < 64)
    feat[b*512 + dg*64 + t] =
        (part[0][t] + part[1][t] + part[2][t] + part[3][t]) * (1.f/256.f);
}

// ---- head: LN + fc1/relu + fc2; 4 blocks ----
__global__ __launch_bounds__(512) void head_kernel(const float* __restrict__ feat,
    const float* __restrict__ lnw, const float* __restrict__ lnb,
    const float* __restrict__ fc1w, const float* __restrict__ fc1b,
    const float* __restrict__ fc2w, const float* __restrict__ fc2b,
    float* __restrict__ out){
  __shared__ float sc[16];
  __shared__ float cbuf[512];
  __shared__ float rbuf[512];
  int b = blockIdx.x, t = threadIdx.x;
  float v = feat[b*512 + t];
  float s = v, ss = v*v;
  block_reduce2(s, ss, sc, 8);
  float mean = s * (1.f/512.f);
  float var = ss * (1.f/512.f) - mean*mean;
  float inv = rsqrtf(var + 1e-5f);
  cbuf[t] = (v - mean)*inv*lnw[t] + lnb[t];
  __syncthreads();
  float a = fc1b[t];
  const float* w1 = fc1w + (size_t)t*512;
  for (int i = 0; i < 512; i += 8){
    float4 w0 = *(const float4*)(w1 + i);
    float4 w4 = *(const float4*)(w1 + i + 4);
    float wf[8] = {w0.x,w0.y,w0.z,w0.w,w4.x,w4.y,w4.z,w4.w};
#pragma unroll
    for (int j = 0; j < 8; ++j) a = fmaf(cbuf[i + j], wf[j], a);
  }
  rbuf[t] = fmaxf(a, 0.f);
  __syncthreads();
  if (t < 10){
    float a2 = fc2b[t];
    const float* w2 = fc2w + (size_t)t*512;
    for (int i = 0; i < 512; ++i) a2 = fmaf(rbuf[i], w2[i], a2);
    out[b*10 + t] = a2;
  }
}

extern "C" void kernel_launch(void* const* d_in, const int* in_sizes, int n_in,
                              void* d_out, int out_size, void* d_ws, size_t ws_size,
                              hipStream_t stream) {
  (void)in_sizes; (void)n_in; (void)out_size; (void)ws_size;
  const float* x          = (const float*)d_in[0];
  const float* patch_w    = (const float*)d_in[1];
  const float* patch_b    = (const float*)d_in[2];
  const float* in_proj_w  = (const float*)d_in[3];
  const float* conv_w_f   = (const float*)d_in[4];
  const float* conv_b_f   = (const float*)d_in[5];
  const float* xproj_w_f  = (const float*)d_in[6];
  const float* dtproj_w_f = (const float*)d_in[7];
  const float* dtproj_b_f = (const float*)d_in[8];
  const float* A_log_f    = (const float*)d_in[9];
  const float* D_f        = (const float*)d_in[10];
  const float* conv_w_b   = (const float*)d_in[11];
  const float* conv_b_b   = (const float*)d_in[12];
  const float* xproj_w_b  = (const float*)d_in[13];
  const float* dtproj_w_b = (const float*)d_in[14];
  const float* dtproj_b_b = (const float*)d_in[15];
  const float* A_log_b    = (const float*)d_in[16];
  const float* D_b        = (const float*)d_in[17];
  const float* out_proj_w = (const float*)d_in[18];
  const float* norm_w     = (const float*)d_in[19];
  const float* norm_b     = (const float*)d_in[20];
  const float* normf_w    = (const float*)d_in[21];
  const float* normf_b    = (const float*)d_in[22];
  const float* ln_w       = (const float*)d_in[23];
  const float* ln_b       = (const float*)d_in[24];
  const float* fc1_w      = (const float*)d_in[25];
  const float* fc1_b      = (const float*)d_in[26];
  const float* fc2_w      = (const float*)d_in[27];
  const float* fc2_b      = (const float*)d_in[28];

  float* ws   = (float*)d_ws;
  float* hbuf = ws;                       // [0, 524288)
  float* xz   = ws + 524288;              // [524288, 2621440)
  u16*   uHi  = (u16*)(ws + 2621440);     // 2M u16
  u16*   uLo  = (u16*)(ws + 3670016);     // 2M u16
  float* xdbl = ws + 4718592;             // 131072
  float* dtbuf= ws + 4849664;             // 2M
  float* ybuf = ws + 6946816;             // 2M; xw/dtw alias its head (pre-scan)
  u16*   xwHi = (u16*)(ws + 6946816);     // 131072 u16
  u16*   xwLo = (u16*)(ws + 7012352);     // 131072 u16
  u16*   dtwHi= (u16*)(ws + 7077888);     // 65536 u16
  u16*   dtwLo= (u16*)(ws + 7110656);     // 65536 u16
  float* hn   = ws + 9043968;             // 524288 ; xnHi/xnLo alias
  u16*   inHi = (u16*)(ws + 9568256);
  u16*   inLo = (u16*)(ws + 10092544);
  u16*   outHi= (u16*)(ws + 10616832);
  u16*   outLo= (u16*)(ws + 10878976);
  float* feat = ws + 11141120;
  u16*   xnHi = (u16*)hn;
  u16*   xnLo = (u16*)(ws + 9306112);
  u16*   gHi  = (u16*)(ws + 2621440);     // reuse u region after scan
  u16*   gLo  = (u16*)(ws + 3145728);

  patch_embed<<<256, 256, 0, stream>>>(x, patch_w, patch_b, hbuf);
  for (int i = 0; i < 4; ++i){
    convert_w<<<1728, 256, 0, stream>>>(
        in_proj_w + (size_t)i*1048576, out_proj_w + (size_t)i*524288,
        xproj_w_f + (size_t)i*65536, xproj_w_b + (size_t)i*65536,
        dtproj_w_f + (size_t)i*32768, dtproj_w_b + (size_t)i*32768,
        inHi, inLo, outHi, outLo, xwHi, xwLo, dtwHi, dtwLo);
    prep_ln<<<1024, 256, 0, stream>>>(hbuf, norm_w, norm_b, i*512, xnHi, xnLo);
    gemm_bf16<<<dim3(32, 16), 256, 0, stream>>>(
        xnHi, xnLo, 512, inHi, inLo, 512, xz, 2048, 512, 0);
    conv_silu_split<<<512, 256, 0, stream>>>(
        xz, conv_w_f, conv_b_f, conv_w_b, conv_b_b, i*4096, i*1024, uHi, uLo);
    hipMemsetAsync(xdbl, 0, 131072*sizeof(float), stream);
    gemm_xproj_splitk<<<dim3(4, 32), 256, 0, stream>>>(
        uHi, uLo, xwHi, xwLo, xdbl);
    gemm_dt<<<dim3(16, 32), 256, 0, stream>>>(
        xdbl, dtwHi, dtwLo, dtproj_b_f, dtproj_b_b, i*1024, dtbuf);
    scan_coal<<<512, 256, 0, stream>>>(
        dtbuf, uHi, uLo, xdbl, A_log_f, A_log_b, D_f, D_b, i*16384, i*1024, ybuf);
    prep_gate<<<1024, 256, 0, stream>>>(ybuf, xz, gHi, gLo);
    gemm_bf16<<<dim3(8, 16), 256, 0, stream>>>(
        gHi, gLo, 1024, outHi, outLo, 1024, hbuf, 512, 1024, 1);
  }
  ln_kernel<<<1024, 256, 0, stream>>>(hbuf, normf_w, normf_b, hn);
  pool_kernel<<<32, 256, 0, stream>>>(hn, feat);
  head_kernel<<<4, 512, 0, stream>>>(feat, ln_w, ln_b, fc1_w, fc1_b, fc2_w, fc2_b,
                                     (float*)d_out);
}

// Round 13
// 637.375 us; speedup vs baseline: 1.6916x; 1.0238x over previous
//
#include <hip/hip_runtime.h>

// AudioMamba forward. GEMMs = pre-split bf16 MFMA (hi/lo, 3 MFMAs,
// fp32-accurate), padded LDS. xproj = split-K (4 chunks, atomicAdd fp32).
// Weights for ALL layers split once per call (convert_w_all); xdbl zeroing
// folded into prep_ln. Inputs fp32, output fp32.
// B=4, L=256, DM=512, DI=1024, S=16, R=32, DEPTH=4.

#define BB 4
#define LL 256
#define DM 512
#define DI 1024
#define LDST 40   // LDS row stride in u16 (pad 32->40 kills bank conflicts)

typedef unsigned short u16;
typedef unsigned int u32;
typedef __attribute__((ext_vector_type(8))) short s8v;   // 8 bf16 (4 VGPRs)
typedef __attribute__((ext_vector_type(4))) float f4v;   // MFMA accumulator

__device__ __forceinline__ float silu_f(float x){ return x/(1.f+__expf(-x)); }
__device__ __forceinline__ float b2f(u16 u){
  union { u32 i; float f; } v; v.i = ((u32)u) << 16; return v.f;
}
__device__ __forceinline__ void b2x2(u32 w, float& lo, float& hi){
  union { u32 i; float f; } a, b;
  a.i = w << 16; b.i = w & 0xffff0000u;
  lo = a.f; hi = b.f;
}
__device__ __forceinline__ u16 f2bf(float f){
  union { float f; u32 u; } v; v.f = f;
  u32 r = (v.u + 0x7fffu + ((v.u >> 16) & 1u)) >> 16;
  return (u16)r;
}
__device__ __forceinline__ void split8(const float* f, s8v& hi, s8v& lo){
#pragma unroll
  for (int j = 0; j < 8; ++j){
    u16 h = f2bf(f[j]);
    float hf = b2f(h);
    hi[j] = (short)h;
    lo[j] = (short)f2bf(f[j] - hf);
  }
}

// sum over 16-lane DPP row; full sum lands in lane 15 of each row (VALU-only)
__device__ __forceinline__ float row_sum16(float p){
  union { float f; int i; } v, r;
  v.f = p;
  r.i = __builtin_amdgcn_update_dpp(0, v.i, 0x111, 0xF, 0xF, true); v.f += r.f;
  r.i = __builtin_amdgcn_update_dpp(0, v.i, 0x112, 0xF, 0xF, true); v.f += r.f;
  r.i = __builtin_amdgcn_update_dpp(0, v.i, 0x114, 0xF, 0xF, true); v.f += r.f;
  r.i = __builtin_amdgcn_update_dpp(0, v.i, 0x118, 0xF, 0xF, true); v.f += r.f;
  return v.f;
}

__device__ __forceinline__ void block_reduce2(float& a, float& b, float* sc, int nw){
  int lane = threadIdx.x & 63, wid = threadIdx.x >> 6;
#pragma unroll
  for (int o = 32; o > 0; o >>= 1){
    a += __shfl_down(a, o, 64);
    b += __shfl_down(b, o, 64);
  }
  if (lane == 0){ sc[wid*2] = a; sc[wid*2+1] = b; }
  __syncthreads();
  float ta = 0.f, tb = 0.f;
  for (int i = 0; i < nw; ++i){ ta += sc[i*2]; tb += sc[i*2+1]; }
  a = ta; b = tb;
}

// ---- ALL-layer weight split (one launch): grid (1728, 4=layer) ----
__global__ __launch_bounds__(256) void convert_w_all(const float* __restrict__ inW,
    const float* __restrict__ outW, const float* __restrict__ xwF,
    const float* __restrict__ xwB, const float* __restrict__ dtwF,
    const float* __restrict__ dtwB, u16* __restrict__ inHi, u16* __restrict__ inLo,
    u16* __restrict__ outHi, u16* __restrict__ outLo, u16* __restrict__ xwHi,
    u16* __restrict__ xwLo, u16* __restrict__ dtwHi, u16* __restrict__ dtwLo){
  int lay = blockIdx.y;
  int idx = blockIdx.x*256 + threadIdx.x;
  const float4* src; ushort4* dh; ushort4* dl;
  if (idx < 262144){
    src = (const float4*)(inW + (size_t)lay*1048576) + idx;
    dh = (ushort4*)(inHi + (size_t)lay*1048576) + idx;
    dl = (ushort4*)(inLo + (size_t)lay*1048576) + idx;
  } else if (idx < 393216){
    int j = idx - 262144;
    src = (const float4*)(outW + (size_t)lay*524288) + j;
    dh = (ushort4*)(outHi + (size_t)lay*524288) + j;
    dl = (ushort4*)(outLo + (size_t)lay*524288) + j;
  } else if (idx < 409600){
    int j = idx - 393216;
    src = (const float4*)(xwF + (size_t)lay*65536) + j;
    dh = (ushort4*)(xwHi + (size_t)lay*131072) + j;
    dl = (ushort4*)(xwLo + (size_t)lay*131072) + j;
  } else if (idx < 425984){
    int j = idx - 409600;
    src = (const float4*)(xwB + (size_t)lay*65536) + j;
    dh = (ushort4*)(xwHi + (size_t)lay*131072 + 65536) + j;
    dl = (ushort4*)(xwLo + (size_t)lay*131072 + 65536) + j;
  } else if (idx < 434176){
    int j = idx - 425984;
    src = (const float4*)(dtwF + (size_t)lay*32768) + j;
    dh = (ushort4*)(dtwHi + (size_t)lay*65536) + j;
    dl = (ushort4*)(dtwLo + (size_t)lay*65536) + j;
  } else {
    int j = idx - 434176;
    src = (const float4*)(dtwB + (size_t)lay*32768) + j;
    dh = (ushort4*)(dtwHi + (size_t)lay*65536 + 32768) + j;
    dl = (ushort4*)(dtwLo + (size_t)lay*65536 + 32768) + j;
  }
  float4 v = *src;
  ushort4 h, l;
  h.x = f2bf(v.x); l.x = f2bf(v.x - b2f(h.x));
  h.y = f2bf(v.y); l.y = f2bf(v.y - b2f(h.y));
  h.z = f2bf(v.z); l.z = f2bf(v.z - b2f(h.z));
  h.w = f2bf(v.w); l.w = f2bf(v.w - b2f(h.w));
  *dh = h; *dl = l;
}

// ---- patch embed: 256 blocks (b4, ph8, pg4, dhalf2); 8 tokens per block ----
__global__ __launch_bounds__(256) void patch_embed(const float* __restrict__ x,
    const float* __restrict__ pw, const float* __restrict__ pb, float* __restrict__ h){
  __shared__ float xs[8*256];
  int blk = blockIdx.x;
  int b = blk >> 6, ph = (blk >> 3) & 7, pg = (blk >> 1) & 3, dh = blk & 1;
  int t = threadIdx.x;
  for (int idx = t; idx < 2048; idx += 256){
    int j = idx >> 8, pix = idx & 255, p = pix >> 4, q = pix & 15;
    xs[idx] = x[(size_t)(b*128 + ph*16 + p)*512 + pg*128 + j*16 + q];
  }
  __syncthreads();
  int d = dh*256 + t;
  float acc[8] = {};
  const float* wr = pw + (size_t)d*256;
  for (int i = 0; i < 256; i += 8){
    float4 w0 = *(const float4*)(wr + i);
    float4 w1 = *(const float4*)(wr + i + 4);
    float wf[8] = {w0.x,w0.y,w0.z,w0.w,w1.x,w1.y,w1.z,w1.w};
#pragma unroll
    for (int j = 0; j < 8; ++j){
#pragma unroll
      for (int jj = 0; jj < 8; ++jj)
        acc[j] = fmaf(xs[j*256 + i + jj], wf[jj], acc[j]);
    }
  }
  float bias = pb[d];
#pragma unroll
  for (int j = 0; j < 8; ++j)
    h[(size_t)(b*256 + ph*32 + pg*8 + j)*512 + d] = acc[j] + bias;
}

// ---- prep_ln: LN(h) -> bf16 hi/lo; also zeroes xdbl (for split-K atomics) ----
__global__ __launch_bounds__(256) void prep_ln(const float* __restrict__ x,
    const float* __restrict__ w, const float* __restrict__ bias, int wOff,
    u16* __restrict__ hiO, u16* __restrict__ loO, float* __restrict__ xdblZ){
  __shared__ float sc[8];
  int row = blockIdx.x, t = threadIdx.x;
  if (t < 128) xdblZ[(size_t)row*128 + t] = 0.f;
  const float* xr = x + (size_t)row*DM;
  float v0 = xr[t], v1 = xr[t + 256];
  float s = v0 + v1, ss = v0*v0 + v1*v1;
  block_reduce2(s, ss, sc, 4);
  float mean = s * (1.f/512.f);
  float var = ss * (1.f/512.f) - mean*mean;
  float inv = rsqrtf(var + 1e-5f);
  float o0 = (v0 - mean)*inv*w[wOff + t]       + bias[wOff + t];
  float o1 = (v1 - mean)*inv*w[wOff + t + 256] + bias[wOff + t + 256];
  u16 h0 = f2bf(o0), h1 = f2bf(o1);
  hiO[(size_t)row*DM + t]       = h0;
  hiO[(size_t)row*DM + t + 256] = h1;
  loO[(size_t)row*DM + t]       = f2bf(o0 - b2f(h0));
  loO[(size_t)row*DM + t + 256] = f2bf(o1 - b2f(h1));
}

// ---- prep_gate: g = (yf+yb)*silu(z) -> bf16 hi/lo; one block per row ----
__global__ __launch_bounds__(256) void prep_gate(const float* __restrict__ ybuf,
    const float* __restrict__ xz, u16* __restrict__ gHi, u16* __restrict__ gLo){
  int row = blockIdx.x, t = threadIdx.x;
  int c = t*4;
  float4 yf = *(const float4*)(ybuf + (size_t)row*DI + c);
  float4 yb = *(const float4*)(ybuf + 1048576 + (size_t)row*DI + c);
  float4 zv = *(const float4*)(xz + (size_t)row*2048 + 1024 + c);
  float g0 = (yf.x + yb.x)*silu_f(zv.x);
  float g1 = (yf.y + yb.y)*silu_f(zv.y);
  float g2 = (yf.z + yb.z)*silu_f(zv.z);
  float g3 = (yf.w + yb.w)*silu_f(zv.w);
  ushort4 h, l;
  h.x = f2bf(g0); l.x = f2bf(g0 - b2f(h.x));
  h.y = f2bf(g1); l.y = f2bf(g1 - b2f(h.y));
  h.z = f2bf(g2); l.z = f2bf(g2 - b2f(h.z));
  h.w = f2bf(g3); l.w = f2bf(g3 - b2f(h.w));
  *(ushort4*)(gHi + (size_t)row*DI + c) = h;
  *(ushort4*)(gLo + (size_t)row*DI + c) = l;
}

// ---- generic pre-split-bf16 MFMA GEMM: C(M,N) (+)= A(M,K) @ B(N,K)^T ----
__global__ __launch_bounds__(256) void gemm_bf16(const u16* __restrict__ Ahi_g,
    const u16* __restrict__ Alo_g, int As, const u16* __restrict__ Bhi_g,
    const u16* __restrict__ Blo_g, int Bs, float* __restrict__ C, int Cs,
    int K, int addFlag){
  __shared__ __align__(16) u16 Ah[64*LDST], Al[64*LDST], Bh[64*LDST], Bl[64*LDST];
  int bm = blockIdx.y*64, bn = blockIdx.x*64;
  int t = threadIdx.x;
  int sr = t >> 2, sc8 = (t & 3)*8;
  int lane = t & 63, wv = t >> 6, ml = lane & 15, quad = lane >> 4;
  int mq = wv >> 1, nq = wv & 1;
  f4v acc[2][2] = {};
  for (int k0 = 0; k0 < K; k0 += 32){
    *(uint4*)&Ah[sr*LDST + sc8] = *(const uint4*)(Ahi_g + (size_t)(bm + sr)*As + k0 + sc8);
    *(uint4*)&Al[sr*LDST + sc8] = *(const uint4*)(Alo_g + (size_t)(bm + sr)*As + k0 + sc8);
    *(uint4*)&Bh[sr*LDST + sc8] = *(const uint4*)(Bhi_g + (size_t)(bn + sr)*Bs + k0 + sc8);
    *(uint4*)&Bl[sr*LDST + sc8] = *(const uint4*)(Blo_g + (size_t)(bn + sr)*Bs + k0 + sc8);
    __syncthreads();
    s8v ah[2], al2[2], bh2[2], bl2[2];
#pragma unroll
    for (int mt = 0; mt < 2; ++mt){
      int row = mq*32 + mt*16 + ml;
      ah[mt]  = *(s8v*)&Ah[row*LDST + quad*8];
      al2[mt] = *(s8v*)&Al[row*LDST + quad*8];
    }
#pragma unroll
    for (int nt = 0; nt < 2; ++nt){
      int col = nq*32 + nt*16 + ml;
      bh2[nt] = *(s8v*)&Bh[col*LDST + quad*8];
      bl2[nt] = *(s8v*)&Bl[col*LDST + quad*8];
    }
#pragma unroll
    for (int mt = 0; mt < 2; ++mt)
#pragma unroll
      for (int nt = 0; nt < 2; ++nt){
        acc[mt][nt] = __builtin_amdgcn_mfma_f32_16x16x32_bf16(ah[mt],  bh2[nt], acc[mt][nt], 0, 0, 0);
        acc[mt][nt] = __builtin_amdgcn_mfma_f32_16x16x32_bf16(al2[mt], bh2[nt], acc[mt][nt], 0, 0, 0);
        acc[mt][nt] = __builtin_amdgcn_mfma_f32_16x16x32_bf16(ah[mt],  bl2[nt], acc[mt][nt], 0, 0, 0);
      }
    __syncthreads();
  }
#pragma unroll
  for (int mt = 0; mt < 2; ++mt)
#pragma unroll
    for (int nt = 0; nt < 2; ++nt)
#pragma unroll
      for (int r = 0; r < 4; ++r){
        float* cp = C + (size_t)(bm + mq*32 + mt*16 + quad*4 + r)*Cs +
                    bn + nq*32 + nt*16 + ml;
        if (addFlag) *cp += acc[mt][nt][r];
        else         *cp  = acc[mt][nt][r];
      }
}

// ---- conv (K=4 causal depthwise) + SiLU -> u as bf16 hi/lo ----
__global__ __launch_bounds__(256) void conv_silu_split(const float* __restrict__ xz,
    const float* __restrict__ cwF, const float* __restrict__ cbF,
    const float* __restrict__ cwB, const float* __restrict__ cbB,
    int cwOff, int cbOff, u16* __restrict__ uHi, u16* __restrict__ uLo){
  int blk = blockIdx.x;
  int dir = blk >> 8, rem = blk & 255, b = rem >> 6, lg = rem & 63;
  int l0 = lg*4;
  const float* cw = dir ? cwB : cwF;
  const float* cb = dir ? cbB : cbF;
  int t = threadIdx.x;
  int rbase = (dir*BB + b)*LL;
  for (int dd = 0; dd < 4; ++dd){
    int d = t + dd*256;
    float4 w4 = *(const float4*)(cw + cwOff + d*4);
    float wf[4] = {w4.x, w4.y, w4.z, w4.w};
    float bias = cb[cbOff + d];
#pragma unroll
    for (int r = 0; r < 4; ++r){
      int l = l0 + r;
      float acc = bias;
#pragma unroll
      for (int k = 0; k < 4; ++k){
        int li = l + k - 3;
        if (li >= 0){
          int sl = dir ? (LL-1-li) : li;
          acc = fmaf(xz[(size_t)(b*LL + sl)*2048 + d], wf[k], acc);
        }
      }
      float uval = silu_f(acc);
      u16 h = f2bf(uval);
      uHi[(size_t)(rbase + l)*DI + d] = h;
      uLo[(size_t)(rbase + l)*DI + d] = f2bf(uval - b2f(h));
    }
  }
}

// ---- xproj split-K: xdbl(2048,64) += u(2048,1024)@xw(64,1024)^T over k-chunk ----
// grid (4 kchunks, 32 mtiles) = 128 blocks; fp32 atomicAdd into zeroed xdbl.
__global__ __launch_bounds__(256) void gemm_xproj_splitk(const u16* __restrict__ uHi,
    const u16* __restrict__ uLo, const u16* __restrict__ xwHi,
    const u16* __restrict__ xwLo, float* __restrict__ xdbl){
  __shared__ __align__(16) u16 Ah[64*LDST], Al[64*LDST], Bh[64*LDST], Bl[64*LDST];
  int bm = blockIdx.y*64;
  int kc = blockIdx.x;
  int dir = bm >> 10;
  const u16* BhG = xwHi + dir*65536;
  const u16* BlG = xwLo + dir*65536;
  int t = threadIdx.x;
  int sr = t >> 2, sc8 = (t & 3)*8;
  int lane = t & 63, wv = t >> 6, ml = lane & 15, quad = lane >> 4;
  int mq = wv >> 1, nq = wv & 1;
  f4v acc[2][2] = {};
  for (int k0 = kc*256; k0 < kc*256 + 256; k0 += 32){
    *(uint4*)&Ah[sr*LDST + sc8] = *(const uint4*)(uHi + (size_t)(bm + sr)*1024 + k0 + sc8);
    *(uint4*)&Al[sr*LDST + sc8] = *(const uint4*)(uLo + (size_t)(bm + sr)*1024 + k0 + sc8);
    *(uint4*)&Bh[sr*LDST + sc8] = *(const uint4*)(BhG + (size_t)sr*1024 + k0 + sc8);
    *(uint4*)&Bl[sr*LDST + sc8] = *(const uint4*)(BlG + (size_t)sr*1024 + k0 + sc8);
    __syncthreads();
    s8v ah[2], al2[2], bh2[2], bl2[2];
#pragma unroll
    for (int mt = 0; mt < 2; ++mt){
      int row = mq*32 + mt*16 + ml;
      ah[mt]  = *(s8v*)&Ah[row*LDST + quad*8];
      al2[mt] = *(s8v*)&Al[row*LDST + quad*8];
    }
#pragma unroll
    for (int nt = 0; nt < 2; ++nt){
      int col = nq*32 + nt*16 + ml;
      bh2[nt] = *(s8v*)&Bh[col*LDST + quad*8];
      bl2[nt] = *(s8v*)&Bl[col*LDST + quad*8];
    }
#pragma unroll
    for (int mt = 0; mt < 2; ++mt)
#pragma unroll
      for (int nt = 0; nt < 2; ++nt){
        acc[mt][nt] = __builtin_amdgcn_mfma_f32_16x16x32_bf16(ah[mt],  bh2[nt], acc[mt][nt], 0, 0, 0);
        acc[mt][nt] = __builtin_amdgcn_mfma_f32_16x16x32_bf16(al2[mt], bh2[nt], acc[mt][nt], 0, 0, 0);
        acc[mt][nt] = __builtin_amdgcn_mfma_f32_16x16x32_bf16(ah[mt],  bl2[nt], acc[mt][nt], 0, 0, 0);
      }
    __syncthreads();
  }
#pragma unroll
  for (int mt = 0; mt < 2; ++mt)
#pragma unroll
    for (int nt = 0; nt < 2; ++nt)
#pragma unroll
      for (int r = 0; r < 4; ++r)
        atomicAdd(xdbl + (size_t)(bm + mq*32 + mt*16 + quad*4 + r)*64 +
                  nq*32 + nt*16 + ml, acc[mt][nt][r]);
}

// ---- dt GEMM: dt(2048,1024) = softplus(xdbl[:, :32] @ dtw(1024,32)^T + b) ----
__global__ __launch_bounds__(256) void gemm_dt(const float* __restrict__ xdbl,
    const u16* __restrict__ dtwHi, const u16* __restrict__ dtwLo,
    const float* __restrict__ dtbF, const float* __restrict__ dtbB, int bOff,
    float* __restrict__ dtOut){
  __shared__ __align__(16) u16 Ah[64*LDST], Al[64*LDST], Bh[64*LDST], Bl[64*LDST];
  int bm = blockIdx.y*64, bn = blockIdx.x*64;
  int dir = bm >> 10;
  const u16* BhG = dtwHi + dir*32768;
  const u16* BlG = dtwLo + dir*32768;
  const float* dtb = dir ? dtbB : dtbF;
  int t = threadIdx.x;
  int sr = t >> 2, sc8 = (t & 3)*8;
  int lane = t & 63, wv = t >> 6, ml = lane & 15, quad = lane >> 4;
  int mq = wv >> 1, nq = wv & 1;
  {
    const float* ap = xdbl + (size_t)(bm + sr)*64 + sc8;
    float4 a0 = *(const float4*)ap;
    float4 a1 = *(const float4*)(ap + 4);
    float af[8] = {a0.x,a0.y,a0.z,a0.w,a1.x,a1.y,a1.z,a1.w};
    s8v hi, lo; split8(af, hi, lo);
    *(s8v*)&Ah[sr*LDST + sc8] = hi;
    *(s8v*)&Al[sr*LDST + sc8] = lo;
  }
  *(uint4*)&Bh[sr*LDST + sc8] = *(const uint4*)(BhG + (size_t)(bn + sr)*32 + sc8);
  *(uint4*)&Bl[sr*LDST + sc8] = *(const uint4*)(BlG + (size_t)(bn + sr)*32 + sc8);
  __syncthreads();
  f4v acc[2][2] = {};
  s8v ah[2], al2[2], bh2[2], bl2[2];
#pragma unroll
  for (int mt = 0; mt < 2; ++mt){
    int row = mq*32 + mt*16 + ml;
    ah[mt]  = *(s8v*)&Ah[row*LDST + quad*8];
    al2[mt] = *(s8v*)&Al[row*LDST + quad*8];
  }
#pragma unroll
  for (int nt = 0; nt < 2; ++nt){
    int col = nq*32 + nt*16 + ml;
    bh2[nt] = *(s8v*)&Bh[col*LDST + quad*8];
    bl2[nt] = *(s8v*)&Bl[col*LDST + quad*8];
  }
#pragma unroll
  for (int mt = 0; mt < 2; ++mt)
#pragma unroll
    for (int nt = 0; nt < 2; ++nt){
      acc[mt][nt] = __builtin_amdgcn_mfma_f32_16x16x32_bf16(ah[mt],  bh2[nt], acc[mt][nt], 0, 0, 0);
      acc[mt][nt] = __builtin_amdgcn_mfma_f32_16x16x32_bf16(al2[mt], bh2[nt], acc[mt][nt], 0, 0, 0);
      acc[mt][nt] = __builtin_amdgcn_mfma_f32_16x16x32_bf16(ah[mt],  bl2[nt], acc[mt][nt], 0, 0, 0);
    }
#pragma unroll
  for (int mt = 0; mt < 2; ++mt)
#pragma unroll
    for (int nt = 0; nt < 2; ++nt){
      int col = bn + nq*32 + nt*16 + ml;
      float bias = dtb[bOff + col];
#pragma unroll
      for (int r = 0; r < 4; ++r){
        int row = bm + mq*32 + mt*16 + quad*4 + r;
        float sv = acc[mt][nt][r] + bias;
        dtOut[(size_t)row*1024 + col] = (sv > 15.f) ? sv : log1pf(__expf(sv));
      }
    }
}

// ---- coalesced LDS-tiled selective scan (u reconstructed from bf16 hi/lo) ----
__global__ __launch_bounds__(256) void scan_coal(const float* __restrict__ dt,
    const u16* __restrict__ uHi, const u16* __restrict__ uLo,
    const float* __restrict__ xd,
    const float* __restrict__ AlogF, const float* __restrict__ AlogB,
    const float* __restrict__ DF, const float* __restrict__ DB,
    int aOff, int dOff, float* __restrict__ y){
  __shared__ __align__(16) float dtuT[16][516];
  __shared__ __align__(16) float BCT[16][516];
  __shared__ __align__(16) float ytile[128][16];
  int blk = blockIdx.x;
  int dir = blk >> 8, b = (blk >> 6) & 3, dg = blk & 63;
  int t = threadIdx.x;
  int rbase = (dir*BB + b)*LL;
  const float* Alog = dir ? AlogB : AlogF;
  const float* Dpt  = dir ? DB : DF;
  {
    int q = t & 3, lb = t >> 2;
    for (int pass = 0; pass < 4; ++pass){
      int l = pass*64 + lb;
      size_t base = (size_t)(rbase + l)*DI + dg*16 + q*4;
      float4 dv = *(const float4*)(dt + base);
      uint2 uh = *(const uint2*)(uHi + base);
      uint2 ul = *(const uint2*)(uLo + base);
      float h0,h1,h2,h3,l0f,l1f,l2f,l3f;
      b2x2(uh.x, h0, h1); b2x2(uh.y, h2, h3);
      b2x2(ul.x, l0f, l1f); b2x2(ul.y, l2f, l3f);
      float2 p0 = {dv.x, h0 + l0f}, p1 = {dv.y, h1 + l1f};
      float2 p2 = {dv.z, h2 + l2f}, p3 = {dv.w, h3 + l3f};
      *(float2*)&dtuT[q*4+0][l*2] = p0;
      *(float2*)&dtuT[q*4+1][l*2] = p1;
      *(float2*)&dtuT[q*4+2][l*2] = p2;
      *(float2*)&dtuT[q*4+3][l*2] = p3;
    }
  }
  {
    int h8 = t & 7, lb = t >> 3;
    for (int pass = 0; pass < 8; ++pass){
      int l = pass*32 + lb;
      float4 v = *(const float4*)(xd + (size_t)(rbase + l)*64 + 32 + h8*4);
      if (h8 < 4){
        int s0 = h8*4;
        BCT[s0+0][l*2] = v.x; BCT[s0+1][l*2] = v.y;
        BCT[s0+2][l*2] = v.z; BCT[s0+3][l*2] = v.w;
      } else {
        int s0 = (h8-4)*4;
        BCT[s0+0][l*2+1] = v.x; BCT[s0+1][l*2+1] = v.y;
        BCT[s0+2][l*2+1] = v.z; BCT[s0+3][l*2+1] = v.w;
      }
    }
  }
  int s = t & 15, dl = t >> 4;
  float Av = -__expf(Alog[aOff + dg*256 + t]);
  float Dp = Dpt[dOff + dg*16 + dl];
  __syncthreads();
  float h = 0.f;
  for (int half = 0; half < 2; ++half){
    for (int l0 = half*128; l0 < half*128 + 128; l0 += 4){
      float4 du01 = *(const float4*)&dtuT[dl][l0*2];
      float4 du23 = *(const float4*)&dtuT[dl][l0*2 + 4];
      float4 bc01 = *(const float4*)&BCT[s][l0*2];
      float4 bc23 = *(const float4*)&BCT[s][l0*2 + 4];
      float dtv[4] = {du01.x, du01.z, du23.x, du23.z};
      float uv[4]  = {du01.y, du01.w, du23.y, du23.w};
      float Bv[4]  = {bc01.x, bc01.z, bc23.x, bc23.z};
      float Cv[4]  = {bc01.y, bc01.w, bc23.y, bc23.w};
#pragma unroll
      for (int i = 0; i < 4; ++i){
        float a = __expf(dtv[i] * Av);
        h = fmaf(a, h, dtv[i]*uv[i]*Bv[i]);
        float p = h * Cv[i];
        float sum = row_sum16(p);
        if (s == 15){
          int lr = (l0 + i) & 127;
          ytile[lr][dl] = fmaf(uv[i], Dp, sum);
        }
      }
    }
    __syncthreads();
    {
      int d4 = t & 3, lh = t >> 2;
      for (int pass = 0; pass < 2; ++pass){
        int lr = pass*64 + lh;
        int l = half*128 + lr;
        int lo = dir ? (255 - l) : l;
        float4 vv = *(const float4*)&ytile[lr][d4*4];
        *(float4*)(y + (size_t)(rbase + lo)*DI + dg*16 + d4*4) = vv;
      }
    }
    __syncthreads();
  }
}

// ---- final LayerNorm ----
__global__ __launch_bounds__(256) void ln_kernel(const float* __restrict__ x,
    const float* __restrict__ w, const float* __restrict__ bias,
    float* __restrict__ y){
  __shared__ float sc[8];
  int row = blockIdx.x, t = threadIdx.x;
  const float* xr = x + (size_t)row*DM;
  float v0 = xr[t], v1 = xr[t + 256];
  float s = v0 + v1, ss = v0*v0 + v1*v1;
  block_reduce2(s, ss, sc, 4);
  float mean = s * (1.f/512.f);
  float var = ss * (1.f/512.f) - mean*mean;
  float inv = rsqrtf(var + 1e-5f);
  float* yr = y + (size_t)row*DM;
  yr[t]       = (v0 - mean)*inv*w[t]       + bias[t];
  yr[t + 256] = (v1 - mean)*inv*w[t + 256] + bias[t + 256];
}

// ---- pool: mean over L, coalesced; 32 blocks (4 b x 8 d-groups) ----
__global__ __launch_bounds__(256) void pool_kernel(const float* __restrict__ hn,
    float* __restrict__ feat){
  __shared__ float part[4][64];
  int b = blockIdx.x >> 3, dg = blockIdx.x & 7;
  int t = threadIdx.x, dl = t & 63, lq = t >> 6;
  const float* p = hn + (size_t)(b*256 + lq*64)*512 + dg*64 + dl;
  float s = 0.f;
#pragma unroll 4
  for (int i = 0; i < 64; ++i) s += p[(size_t)i*512];
  part[lq][dl] = s;
  __syncthreads();
  if (t < 64)
    feat[b*512 + dg*64 + t] =
        (part[0][t] + part[1][t] + part[2][t] + part[3][t]) * (1.f/256.f);
}

// ---- head: LN + fc1/relu + fc2; 4 blocks ----
__global__ __launch_bounds__(512) void head_kernel(const float* __restrict__ feat,
    const float* __restrict__ lnw, const float* __restrict__ lnb,
    const float* __restrict__ fc1w, const float* __restrict__ fc1b,
    const float* __restrict__ fc2w, const float* __restrict__ fc2b,
    float* __restrict__ out){
  __shared__ float sc[16];
  __shared__ float cbuf[512];
  __shared__ float rbuf[512];
  int b = blockIdx.x, t = threadIdx.x;
  float v = feat[b*512 + t];
  float s = v, ss = v*v;
  block_reduce2(s, ss, sc, 8);
  float mean = s * (1.f/512.f);
  float var = ss * (1.f/512.f) - mean*mean;
  float inv = rsqrtf(var + 1e-5f);
  cbuf[t] = (v - mean)*inv*lnw[t] + lnb[t];
  __syncthreads();
  float a = fc1b[t];
  const float* w1 = fc1w + (size_t)t*512;
  for (int i = 0; i < 512; i += 8){
    float4 w0 = *(const float4*)(w1 + i);
    float4 w4 = *(const float4*)(w1 + i + 4);
    float wf[8] = {w0.x,w0.y,w0.z,w0.w,w4.x,w4.y,w4.z,w4.w};
#pragma unroll
    for (int j = 0; j < 8; ++j) a = fmaf(cbuf[i + j], wf[j], a);
  }
  rbuf[t] = fmaxf(a, 0.f);
  __syncthreads();
  if (t < 10){
    float a2 = fc2b[t];
    const float* w2 = fc2w + (size_t)t*512;
    for (int i = 0; i < 512; ++i) a2 = fmaf(rbuf[i], w2[i], a2);
    out[b*10 + t] = a2;
  }
}

extern "C" void kernel_launch(void* const* d_in, const int* in_sizes, int n_in,
                              void* d_out, int out_size, void* d_ws, size_t ws_size,
                              hipStream_t stream) {
  (void)in_sizes; (void)n_in; (void)out_size; (void)ws_size;
  const float* x          = (const float*)d_in[0];
  const float* patch_w    = (const float*)d_in[1];
  const float* patch_b    = (const float*)d_in[2];
  const float* in_proj_w  = (const float*)d_in[3];
  const float* conv_w_f   = (const float*)d_in[4];
  const float* conv_b_f   = (const float*)d_in[5];
  const float* xproj_w_f  = (const float*)d_in[6];
  const float* dtproj_w_f = (const float*)d_in[7];
  const float* dtproj_b_f = (const float*)d_in[8];
  const float* A_log_f    = (const float*)d_in[9];
  const float* D_f        = (const float*)d_in[10];
  const float* conv_w_b   = (const float*)d_in[11];
  const float* conv_b_b   = (const float*)d_in[12];
  const float* xproj_w_b  = (const float*)d_in[13];
  const float* dtproj_w_b = (const float*)d_in[14];
  const float* dtproj_b_b = (const float*)d_in[15];
  const float* A_log_b    = (const float*)d_in[16];
  const float* D_b        = (const float*)d_in[17];
  const float* out_proj_w = (const float*)d_in[18];
  const float* norm_w     = (const float*)d_in[19];
  const float* norm_b     = (const float*)d_in[20];
  const float* normf_w    = (const float*)d_in[21];
  const float* normf_b    = (const float*)d_in[22];
  const float* ln_w       = (const float*)d_in[23];
  const float* ln_b       = (const float*)d_in[24];
  const float* fc1_w      = (const float*)d_in[25];
  const float* fc1_b      = (const float*)d_in[26];
  const float* fc2_w      = (const float*)d_in[27];
  const float* fc2_b      = (const float*)d_in[28];

  float* ws   = (float*)d_ws;
  float* hbuf = ws;                       // [0, 524288)
  float* xz   = ws + 524288;              // [524288, 2621440)
  u16*   uHi  = (u16*)(ws + 2621440);     // 2M u16
  u16*   uLo  = (u16*)(ws + 3670016);     // 2M u16
  float* xdbl = ws + 4718592;             // 131072
  float* dtbuf= ws + 4849664;             // 2M
  float* ybuf = ws + 6946816;             // 2M
  float* hn   = ws + 9043968;             // 524288 ; xnHi/xnLo alias
  float* feat = ws + 11141120;            // 2048
  u16*   xnHi = (u16*)hn;
  u16*   xnLo = (u16*)(ws + 9306112);
  u16*   gHi  = (u16*)(ws + 2621440);     // reuse u region after scan
  u16*   gLo  = (u16*)(ws + 3145728);
  // ---- all-layer split-weight region (high part of the 256 MB ws) ----
  u16*   inHi4 = (u16*)(ws + 11145216);   // 4 x 1048576 u16
  u16*   inLo4 = (u16*)(ws + 13242368);
  u16*   outHi4= (u16*)(ws + 15339520);   // 4 x 524288 u16
  u16*   outLo4= (u16*)(ws + 16388096);
  u16*   xwHi4 = (u16*)(ws + 17436672);   // 4 x 131072 u16
  u16*   xwLo4 = (u16*)(ws + 17698816);
  u16*   dtwHi4= (u16*)(ws + 17960960);   // 4 x 65536 u16
  u16*   dtwLo4= (u16*)(ws + 18092032);

  convert_w_all<<<dim3(1728, 4), 256, 0, stream>>>(
      in_proj_w, out_proj_w, xproj_w_f, xproj_w_b, dtproj_w_f, dtproj_w_b,
      inHi4, inLo4, outHi4, outLo4, xwHi4, xwLo4, dtwHi4, dtwLo4);
  patch_embed<<<256, 256, 0, stream>>>(x, patch_w, patch_b, hbuf);
  for (int i = 0; i < 4; ++i){
    prep_ln<<<1024, 256, 0, stream>>>(hbuf, norm_w, norm_b, i*512, xnHi, xnLo, xdbl);
    gemm_bf16<<<dim3(32, 16), 256, 0, stream>>>(
        xnHi, xnLo, 512, inHi4 + (size_t)i*1048576, inLo4 + (size_t)i*1048576,
        512, xz, 2048, 512, 0);
    conv_silu_split<<<512, 256, 0, stream>>>(
        xz, conv_w_f, conv_b_f, conv_w_b, conv_b_b, i*4096, i*1024, uHi, uLo);
    gemm_xproj_splitk<<<dim3(4, 32), 256, 0, stream>>>(
        uHi, uLo, xwHi4 + (size_t)i*131072, xwLo4 + (size_t)i*131072, xdbl);
    gemm_dt<<<dim3(16, 32), 256, 0, stream>>>(
        xdbl, dtwHi4 + (size_t)i*65536, dtwLo4 + (size_t)i*65536,
        dtproj_b_f, dtproj_b_b, i*1024, dtbuf);
    scan_coal<<<512, 256, 0, stream>>>(
        dtbuf, uHi, uLo, xdbl, A_log_f, A_log_b, D_f, D_b, i*16384, i*1024, ybuf);
    prep_gate<<<1024, 256, 0, stream>>>(ybuf, xz, gHi, gLo);
    gemm_bf16<<<dim3(8, 16), 256, 0, stream>>>(
        gHi, gLo, 1024, outHi4 + (size_t)i*524288, outLo4 + (size_t)i*524288,
        1024, hbuf, 512, 1024, 1);
  }
  ln_kernel<<<1024, 256, 0, stream>>>(hbuf, normf_w, normf_b, hn);
  pool_kernel<<<32, 256, 0, stream>>>(hn, feat);
  head_kernel<<<4, 512, 0, stream>>>(feat, ln_w, ln_b, fc1_w, fc1_b, fc2_w, fc2_b,
                                     (float*)d_out);
}

// Round 14
// 624.931 us; speedup vs baseline: 1.7253x; 1.0199x over previous
//
#include <hip/hip_runtime.h>

// AudioMamba forward. GEMMs = pre-split bf16 MFMA (hi/lo, 3 MFMAs,
// fp32-accurate), padded LDS. xproj = split-K (atomicAdd fp32). dtproj fused
// into the scan's staging (fp32, K=32 per-thread dots). All-layer weight
// split once per call. Inputs fp32, output fp32.
// B=4, L=256, DM=512, DI=1024, S=16, R=32, DEPTH=4.

#define BB 4
#define LL 256
#define DM 512
#define DI 1024
#define LDST 40   // LDS row stride in u16 (pad 32->40 kills bank conflicts)

typedef unsigned short u16;
typedef unsigned int u32;
typedef __attribute__((ext_vector_type(8))) short s8v;   // 8 bf16 (4 VGPRs)
typedef __attribute__((ext_vector_type(4))) float f4v;   // MFMA accumulator

__device__ __forceinline__ float silu_f(float x){ return x/(1.f+__expf(-x)); }
__device__ __forceinline__ float b2f(u16 u){
  union { u32 i; float f; } v; v.i = ((u32)u) << 16; return v.f;
}
__device__ __forceinline__ void b2x2(u32 w, float& lo, float& hi){
  union { u32 i; float f; } a, b;
  a.i = w << 16; b.i = w & 0xffff0000u;
  lo = a.f; hi = b.f;
}
__device__ __forceinline__ u16 f2bf(float f){
  union { float f; u32 u; } v; v.f = f;
  u32 r = (v.u + 0x7fffu + ((v.u >> 16) & 1u)) >> 16;
  return (u16)r;
}
__device__ __forceinline__ void split8(const float* f, s8v& hi, s8v& lo){
#pragma unroll
  for (int j = 0; j < 8; ++j){
    u16 h = f2bf(f[j]);
    float hf = b2f(h);
    hi[j] = (short)h;
    lo[j] = (short)f2bf(f[j] - hf);
  }
}

// sum over 16-lane DPP row; full sum lands in lane 15 of each row (VALU-only)
__device__ __forceinline__ float row_sum16(float p){
  union { float f; int i; } v, r;
  v.f = p;
  r.i = __builtin_amdgcn_update_dpp(0, v.i, 0x111, 0xF, 0xF, true); v.f += r.f;
  r.i = __builtin_amdgcn_update_dpp(0, v.i, 0x112, 0xF, 0xF, true); v.f += r.f;
  r.i = __builtin_amdgcn_update_dpp(0, v.i, 0x114, 0xF, 0xF, true); v.f += r.f;
  r.i = __builtin_amdgcn_update_dpp(0, v.i, 0x118, 0xF, 0xF, true); v.f += r.f;
  return v.f;
}

__device__ __forceinline__ void block_reduce2(float& a, float& b, float* sc, int nw){
  int lane = threadIdx.x & 63, wid = threadIdx.x >> 6;
#pragma unroll
  for (int o = 32; o > 0; o >>= 1){
    a += __shfl_down(a, o, 64);
    b += __shfl_down(b, o, 64);
  }
  if (lane == 0){ sc[wid*2] = a; sc[wid*2+1] = b; }
  __syncthreads();
  float ta = 0.f, tb = 0.f;
  for (int i = 0; i < nw; ++i){ ta += sc[i*2]; tb += sc[i*2+1]; }
  a = ta; b = tb;
}

// ---- ALL-layer weight split (one launch): grid (1728, 4=layer) ----
// (dtw entries still split for layout compatibility; scan uses fp32 dtw now.)
__global__ __launch_bounds__(256) void convert_w_all(const float* __restrict__ inW,
    const float* __restrict__ outW, const float* __restrict__ xwF,
    const float* __restrict__ xwB, const float* __restrict__ dtwF,
    const float* __restrict__ dtwB, u16* __restrict__ inHi, u16* __restrict__ inLo,
    u16* __restrict__ outHi, u16* __restrict__ outLo, u16* __restrict__ xwHi,
    u16* __restrict__ xwLo, u16* __restrict__ dtwHi, u16* __restrict__ dtwLo){
  int lay = blockIdx.y;
  int idx = blockIdx.x*256 + threadIdx.x;
  const float4* src; ushort4* dh; ushort4* dl;
  if (idx < 262144){
    src = (const float4*)(inW + (size_t)lay*1048576) + idx;
    dh = (ushort4*)(inHi + (size_t)lay*1048576) + idx;
    dl = (ushort4*)(inLo + (size_t)lay*1048576) + idx;
  } else if (idx < 393216){
    int j = idx - 262144;
    src = (const float4*)(outW + (size_t)lay*524288) + j;
    dh = (ushort4*)(outHi + (size_t)lay*524288) + j;
    dl = (ushort4*)(outLo + (size_t)lay*524288) + j;
  } else if (idx < 409600){
    int j = idx - 393216;
    src = (const float4*)(xwF + (size_t)lay*65536) + j;
    dh = (ushort4*)(xwHi + (size_t)lay*131072) + j;
    dl = (ushort4*)(xwLo + (size_t)lay*131072) + j;
  } else if (idx < 425984){
    int j = idx - 409600;
    src = (const float4*)(xwB + (size_t)lay*65536) + j;
    dh = (ushort4*)(xwHi + (size_t)lay*131072 + 65536) + j;
    dl = (ushort4*)(xwLo + (size_t)lay*131072 + 65536) + j;
  } else if (idx < 434176){
    int j = idx - 425984;
    src = (const float4*)(dtwF + (size_t)lay*32768) + j;
    dh = (ushort4*)(dtwHi + (size_t)lay*65536) + j;
    dl = (ushort4*)(dtwLo + (size_t)lay*65536) + j;
  } else {
    int j = idx - 434176;
    src = (const float4*)(dtwB + (size_t)lay*32768) + j;
    dh = (ushort4*)(dtwHi + (size_t)lay*65536 + 32768) + j;
    dl = (ushort4*)(dtwLo + (size_t)lay*65536 + 32768) + j;
  }
  float4 v = *src;
  ushort4 h, l;
  h.x = f2bf(v.x); l.x = f2bf(v.x - b2f(h.x));
  h.y = f2bf(v.y); l.y = f2bf(v.y - b2f(h.y));
  h.z = f2bf(v.z); l.z = f2bf(v.z - b2f(h.z));
  h.w = f2bf(v.w); l.w = f2bf(v.w - b2f(h.w));
  *dh = h; *dl = l;
}

// ---- patch embed: 256 blocks (b4, ph8, pg4, dhalf2); 8 tokens per block ----
__global__ __launch_bounds__(256) void patch_embed(const float* __restrict__ x,
    const float* __restrict__ pw, const float* __restrict__ pb, float* __restrict__ h){
  __shared__ float xs[8*256];
  int blk = blockIdx.x;
  int b = blk >> 6, ph = (blk >> 3) & 7, pg = (blk >> 1) & 3, dh = blk & 1;
  int t = threadIdx.x;
  for (int idx = t; idx < 2048; idx += 256){
    int j = idx >> 8, pix = idx & 255, p = pix >> 4, q = pix & 15;
    xs[idx] = x[(size_t)(b*128 + ph*16 + p)*512 + pg*128 + j*16 + q];
  }
  __syncthreads();
  int d = dh*256 + t;
  float acc[8] = {};
  const float* wr = pw + (size_t)d*256;
  for (int i = 0; i < 256; i += 8){
    float4 w0 = *(const float4*)(wr + i);
    float4 w1 = *(const float4*)(wr + i + 4);
    float wf[8] = {w0.x,w0.y,w0.z,w0.w,w1.x,w1.y,w1.z,w1.w};
#pragma unroll
    for (int j = 0; j < 8; ++j){
#pragma unroll
      for (int jj = 0; jj < 8; ++jj)
        acc[j] = fmaf(xs[j*256 + i + jj], wf[jj], acc[j]);
    }
  }
  float bias = pb[d];
#pragma unroll
  for (int j = 0; j < 8; ++j)
    h[(size_t)(b*256 + ph*32 + pg*8 + j)*512 + d] = acc[j] + bias;
}

// ---- prep_ln: LN(h) -> bf16 hi/lo; also zeroes xdbl (for split-K atomics) ----
__global__ __launch_bounds__(256) void prep_ln(const float* __restrict__ x,
    const float* __restrict__ w, const float* __restrict__ bias, int wOff,
    u16* __restrict__ hiO, u16* __restrict__ loO, float* __restrict__ xdblZ){
  __shared__ float sc[8];
  int row = blockIdx.x, t = threadIdx.x;
  if (t < 128) xdblZ[(size_t)row*128 + t] = 0.f;
  const float* xr = x + (size_t)row*DM;
  float v0 = xr[t], v1 = xr[t + 256];
  float s = v0 + v1, ss = v0*v0 + v1*v1;
  block_reduce2(s, ss, sc, 4);
  float mean = s * (1.f/512.f);
  float var = ss * (1.f/512.f) - mean*mean;
  float inv = rsqrtf(var + 1e-5f);
  float o0 = (v0 - mean)*inv*w[wOff + t]       + bias[wOff + t];
  float o1 = (v1 - mean)*inv*w[wOff + t + 256] + bias[wOff + t + 256];
  u16 h0 = f2bf(o0), h1 = f2bf(o1);
  hiO[(size_t)row*DM + t]       = h0;
  hiO[(size_t)row*DM + t + 256] = h1;
  loO[(size_t)row*DM + t]       = f2bf(o0 - b2f(h0));
  loO[(size_t)row*DM + t + 256] = f2bf(o1 - b2f(h1));
}

// ---- prep_gate: g = (yf+yb)*silu(z) -> bf16 hi/lo; one block per row ----
__global__ __launch_bounds__(256) void prep_gate(const float* __restrict__ ybuf,
    const float* __restrict__ xz, u16* __restrict__ gHi, u16* __restrict__ gLo){
  int row = blockIdx.x, t = threadIdx.x;
  int c = t*4;
  float4 yf = *(const float4*)(ybuf + (size_t)row*DI + c);
  float4 yb = *(const float4*)(ybuf + 1048576 + (size_t)row*DI + c);
  float4 zv = *(const float4*)(xz + (size_t)row*2048 + 1024 + c);
  float g0 = (yf.x + yb.x)*silu_f(zv.x);
  float g1 = (yf.y + yb.y)*silu_f(zv.y);
  float g2 = (yf.z + yb.z)*silu_f(zv.z);
  float g3 = (yf.w + yb.w)*silu_f(zv.w);
  ushort4 h, l;
  h.x = f2bf(g0); l.x = f2bf(g0 - b2f(h.x));
  h.y = f2bf(g1); l.y = f2bf(g1 - b2f(h.y));
  h.z = f2bf(g2); l.z = f2bf(g2 - b2f(h.z));
  h.w = f2bf(g3); l.w = f2bf(g3 - b2f(h.w));
  *(ushort4*)(gHi + (size_t)row*DI + c) = h;
  *(ushort4*)(gLo + (size_t)row*DI + c) = l;
}

// ---- generic pre-split-bf16 MFMA GEMM: C(M,N) (+)= A(M,K) @ B(N,K)^T ----
__global__ __launch_bounds__(256) void gemm_bf16(const u16* __restrict__ Ahi_g,
    const u16* __restrict__ Alo_g, int As, const u16* __restrict__ Bhi_g,
    const u16* __restrict__ Blo_g, int Bs, float* __restrict__ C, int Cs,
    int K, int addFlag){
  __shared__ __align__(16) u16 Ah[64*LDST], Al[64*LDST], Bh[64*LDST], Bl[64*LDST];
  int bm = blockIdx.y*64, bn = blockIdx.x*64;
  int t = threadIdx.x;
  int sr = t >> 2, sc8 = (t & 3)*8;
  int lane = t & 63, wv = t >> 6, ml = lane & 15, quad = lane >> 4;
  int mq = wv >> 1, nq = wv & 1;
  f4v acc[2][2] = {};
  for (int k0 = 0; k0 < K; k0 += 32){
    *(uint4*)&Ah[sr*LDST + sc8] = *(const uint4*)(Ahi_g + (size_t)(bm + sr)*As + k0 + sc8);
    *(uint4*)&Al[sr*LDST + sc8] = *(const uint4*)(Alo_g + (size_t)(bm + sr)*As + k0 + sc8);
    *(uint4*)&Bh[sr*LDST + sc8] = *(const uint4*)(Bhi_g + (size_t)(bn + sr)*Bs + k0 + sc8);
    *(uint4*)&Bl[sr*LDST + sc8] = *(const uint4*)(Blo_g + (size_t)(bn + sr)*Bs + k0 + sc8);
    __syncthreads();
    s8v ah[2], al2[2], bh2[2], bl2[2];
#pragma unroll
    for (int mt = 0; mt < 2; ++mt){
      int row = mq*32 + mt*16 + ml;
      ah[mt]  = *(s8v*)&Ah[row*LDST + quad*8];
      al2[mt] = *(s8v*)&Al[row*LDST + quad*8];
    }
#pragma unroll
    for (int nt = 0; nt < 2; ++nt){
      int col = nq*32 + nt*16 + ml;
      bh2[nt] = *(s8v*)&Bh[col*LDST + quad*8];
      bl2[nt] = *(s8v*)&Bl[col*LDST + quad*8];
    }
#pragma unroll
    for (int mt = 0; mt < 2; ++mt)
#pragma unroll
      for (int nt = 0; nt < 2; ++nt){
        acc[mt][nt] = __builtin_amdgcn_mfma_f32_16x16x32_bf16(ah[mt],  bh2[nt], acc[mt][nt], 0, 0, 0);
        acc[mt][nt] = __builtin_amdgcn_mfma_f32_16x16x32_bf16(al2[mt], bh2[nt], acc[mt][nt], 0, 0, 0);
        acc[mt][nt] = __builtin_amdgcn_mfma_f32_16x16x32_bf16(ah[mt],  bl2[nt], acc[mt][nt], 0, 0, 0);
      }
    __syncthreads();
  }
#pragma unroll
  for (int mt = 0; mt < 2; ++mt)
#pragma unroll
    for (int nt = 0; nt < 2; ++nt)
#pragma unroll
      for (int r = 0; r < 4; ++r){
        float* cp = C + (size_t)(bm + mq*32 + mt*16 + quad*4 + r)*Cs +
                    bn + nq*32 + nt*16 + ml;
        if (addFlag) *cp += acc[mt][nt][r];
        else         *cp  = acc[mt][nt][r];
      }
}

// ---- conv (K=4 causal depthwise) + SiLU -> u as bf16 hi/lo ----
__global__ __launch_bounds__(256) void conv_silu_split(const float* __restrict__ xz,
    const float* __restrict__ cwF, const float* __restrict__ cbF,
    const float* __restrict__ cwB, const float* __restrict__ cbB,
    int cwOff, int cbOff, u16* __restrict__ uHi, u16* __restrict__ uLo){
  int blk = blockIdx.x;
  int dir = blk >> 8, rem = blk & 255, b = rem >> 6, lg = rem & 63;
  int l0 = lg*4;
  const float* cw = dir ? cwB : cwF;
  const float* cb = dir ? cbB : cbF;
  int t = threadIdx.x;
  int rbase = (dir*BB + b)*LL;
  for (int dd = 0; dd < 4; ++dd){
    int d = t + dd*256;
    float4 w4 = *(const float4*)(cw + cwOff + d*4);
    float wf[4] = {w4.x, w4.y, w4.z, w4.w};
    float bias = cb[cbOff + d];
#pragma unroll
    for (int r = 0; r < 4; ++r){
      int l = l0 + r;
      float acc = bias;
#pragma unroll
      for (int k = 0; k < 4; ++k){
        int li = l + k - 3;
        if (li >= 0){
          int sl = dir ? (LL-1-li) : li;
          acc = fmaf(xz[(size_t)(b*LL + sl)*2048 + d], wf[k], acc);
        }
      }
      float uval = silu_f(acc);
      u16 h = f2bf(uval);
      uHi[(size_t)(rbase + l)*DI + d] = h;
      uLo[(size_t)(rbase + l)*DI + d] = f2bf(uval - b2f(h));
    }
  }
}

// ---- xproj split-K: xdbl(2048,64) += u(2048,1024)@xw(64,1024)^T over k-chunk ----
__global__ __launch_bounds__(256) void gemm_xproj_splitk(const u16* __restrict__ uHi,
    const u16* __restrict__ uLo, const u16* __restrict__ xwHi,
    const u16* __restrict__ xwLo, float* __restrict__ xdbl){
  __shared__ __align__(16) u16 Ah[64*LDST], Al[64*LDST], Bh[64*LDST], Bl[64*LDST];
  int bm = blockIdx.y*64;
  int kc = blockIdx.x;
  int dir = bm >> 10;
  const u16* BhG = xwHi + dir*65536;
  const u16* BlG = xwLo + dir*65536;
  int t = threadIdx.x;
  int sr = t >> 2, sc8 = (t & 3)*8;
  int lane = t & 63, wv = t >> 6, ml = lane & 15, quad = lane >> 4;
  int mq = wv >> 1, nq = wv & 1;
  f4v acc[2][2] = {};
  for (int k0 = kc*256; k0 < kc*256 + 256; k0 += 32){
    *(uint4*)&Ah[sr*LDST + sc8] = *(const uint4*)(uHi + (size_t)(bm + sr)*1024 + k0 + sc8);
    *(uint4*)&Al[sr*LDST + sc8] = *(const uint4*)(uLo + (size_t)(bm + sr)*1024 + k0 + sc8);
    *(uint4*)&Bh[sr*LDST + sc8] = *(const uint4*)(BhG + (size_t)sr*1024 + k0 + sc8);
    *(uint4*)&Bl[sr*LDST + sc8] = *(const uint4*)(BlG + (size_t)sr*1024 + k0 + sc8);
    __syncthreads();
    s8v ah[2], al2[2], bh2[2], bl2[2];
#pragma unroll
    for (int mt = 0; mt < 2; ++mt){
      int row = mq*32 + mt*16 + ml;
      ah[mt]  = *(s8v*)&Ah[row*LDST + quad*8];
      al2[mt] = *(s8v*)&Al[row*LDST + quad*8];
    }
#pragma unroll
    for (int nt = 0; nt < 2; ++nt){
      int col = nq*32 + nt*16 + ml;
      bh2[nt] = *(s8v*)&Bh[col*LDST + quad*8];
      bl2[nt] = *(s8v*)&Bl[col*LDST + quad*8];
    }
#pragma unroll
    for (int mt = 0; mt < 2; ++mt)
#pragma unroll
      for (int nt = 0; nt < 2; ++nt){
        acc[mt][nt] = __builtin_amdgcn_mfma_f32_16x16x32_bf16(ah[mt],  bh2[nt], acc[mt][nt], 0, 0, 0);
        acc[mt][nt] = __builtin_amdgcn_mfma_f32_16x16x32_bf16(al2[mt], bh2[nt], acc[mt][nt], 0, 0, 0);
        acc[mt][nt] = __builtin_amdgcn_mfma_f32_16x16x32_bf16(ah[mt],  bl2[nt], acc[mt][nt], 0, 0, 0);
      }
    __syncthreads();
  }
#pragma unroll
  for (int mt = 0; mt < 2; ++mt)
#pragma unroll
    for (int nt = 0; nt < 2; ++nt)
#pragma unroll
      for (int r = 0; r < 4; ++r)
        atomicAdd(xdbl + (size_t)(bm + mq*32 + mt*16 + quad*4 + r)*64 +
                  nq*32 + nt*16 + ml, acc[mt][nt][r]);
}

// ---- scan with fused dtproj: dt computed in staging (fp32, K=32/thread) ----
__global__ __launch_bounds__(256) void scan_coal(
    const u16* __restrict__ uHi, const u16* __restrict__ uLo,
    const float* __restrict__ xd,
    const float* __restrict__ dtwF, const float* __restrict__ dtwB,
    const float* __restrict__ dtbF, const float* __restrict__ dtbB,
    const float* __restrict__ AlogF, const float* __restrict__ AlogB,
    const float* __restrict__ DF, const float* __restrict__ DB,
    int dtwOff, int bOff, int aOff, int dOff, float* __restrict__ y){
  __shared__ __align__(16) float dtuT[16][516];
  __shared__ __align__(16) float BCT[16][516];
  __shared__ __align__(16) float ytile[128][16];
  int blk = blockIdx.x;
  int dir = blk >> 8, b = (blk >> 6) & 3, dg = blk & 63;
  int t = threadIdx.x;
  int rbase = (dir*BB + b)*LL;
  const float* Alog = dir ? AlogB : AlogF;
  const float* Dpt  = dir ? DB : DF;
  // --- stage dt (computed) + u (reconstructed): thread = (d_local, lc) ---
  {
    int d_local = t & 15, lc = t >> 4;
    int d = dg*16 + d_local;
    const float* dtw = (dir ? dtwB : dtwF) + dtwOff + (size_t)d*32;
    float wreg[32];
#pragma unroll
    for (int k = 0; k < 32; k += 4){
      float4 w4 = *(const float4*)(dtw + k);
      wreg[k] = w4.x; wreg[k+1] = w4.y; wreg[k+2] = w4.z; wreg[k+3] = w4.w;
    }
    float bias = (dir ? dtbB : dtbF)[bOff + d];
    for (int i = 0; i < 16; ++i){
      int l = lc*16 + i;
      const float* xr = xd + (size_t)(rbase + l)*64;
      float acc = bias;
#pragma unroll
      for (int k = 0; k < 32; k += 4){
        float4 v = *(const float4*)(xr + k);
        acc = fmaf(v.x, wreg[k],   acc);
        acc = fmaf(v.y, wreg[k+1], acc);
        acc = fmaf(v.z, wreg[k+2], acc);
        acc = fmaf(v.w, wreg[k+3], acc);
      }
      float dtv = (acc > 15.f) ? acc : log1pf(__expf(acc));
      size_t ub = (size_t)(rbase + l)*DI + d;
      float uval = b2f(uHi[ub]) + b2f(uLo[ub]);
      float2 pr = {dtv, uval};
      *(float2*)&dtuT[d_local][l*2] = pr;
    }
  }
  // --- stage B/C ---
  {
    int h8 = t & 7, lb = t >> 3;
    for (int pass = 0; pass < 8; ++pass){
      int l = pass*32 + lb;
      float4 v = *(const float4*)(xd + (size_t)(rbase + l)*64 + 32 + h8*4);
      if (h8 < 4){
        int s0 = h8*4;
        BCT[s0+0][l*2] = v.x; BCT[s0+1][l*2] = v.y;
        BCT[s0+2][l*2] = v.z; BCT[s0+3][l*2] = v.w;
      } else {
        int s0 = (h8-4)*4;
        BCT[s0+0][l*2+1] = v.x; BCT[s0+1][l*2+1] = v.y;
        BCT[s0+2][l*2+1] = v.z; BCT[s0+3][l*2+1] = v.w;
      }
    }
  }
  int s = t & 15, dl = t >> 4;
  float Av = -__expf(Alog[aOff + dg*256 + t]);
  float Dp = Dpt[dOff + dg*16 + dl];
  __syncthreads();
  float h = 0.f;
  for (int half = 0; half < 2; ++half){
    for (int l0 = half*128; l0 < half*128 + 128; l0 += 4){
      float4 du01 = *(const float4*)&dtuT[dl][l0*2];
      float4 du23 = *(const float4*)&dtuT[dl][l0*2 + 4];
      float4 bc01 = *(const float4*)&BCT[s][l0*2];
      float4 bc23 = *(const float4*)&BCT[s][l0*2 + 4];
      float dtv[4] = {du01.x, du01.z, du23.x, du23.z};
      float uv[4]  = {du01.y, du01.w, du23.y, du23.w};
      float Bv[4]  = {bc01.x, bc01.z, bc23.x, bc23.z};
      float Cv[4]  = {bc01.y, bc01.w, bc23.y, bc23.w};
#pragma unroll
      for (int i = 0; i < 4; ++i){
        float a = __expf(dtv[i] * Av);
        h = fmaf(a, h, dtv[i]*uv[i]*Bv[i]);
        float p = h * Cv[i];
        float sum = row_sum16(p);
        if (s == 15){
          int lr = (l0 + i) & 127;
          ytile[lr][dl] = fmaf(uv[i], Dp, sum);
        }
      }
    }
    __syncthreads();
    {
      int d4 = t & 3, lh = t >> 2;
      for (int pass = 0; pass < 2; ++pass){
        int lr = pass*64 + lh;
        int l = half*128 + lr;
        int lo = dir ? (255 - l) : l;
        float4 vv = *(const float4*)&ytile[lr][d4*4];
        *(float4*)(y + (size_t)(rbase + lo)*DI + dg*16 + d4*4) = vv;
      }
    }
    __syncthreads();
  }
}

// ---- final LayerNorm ----
__global__ __launch_bounds__(256) void ln_kernel(const float* __restrict__ x,
    const float* __restrict__ w, const float* __restrict__ bias,
    float* __restrict__ y){
  __shared__ float sc[8];
  int row = blockIdx.x, t = threadIdx.x;
  const float* xr = x + (size_t)row*DM;
  float v0 = xr[t], v1 = xr[t + 256];
  float s = v0 + v1, ss = v0*v0 + v1*v1;
  block_reduce2(s, ss, sc, 4);
  float mean = s * (1.f/512.f);
  float var = ss * (1.f/512.f) - mean*mean;
  float inv = rsqrtf(var + 1e-5f);
  float* yr = y + (size_t)row*DM;
  yr[t]       = (v0 - mean)*inv*w[t]       + bias[t];
  yr[t + 256] = (v1 - mean)*inv*w[t + 256] + bias[t + 256];
}

// ---- pool: mean over L, coalesced; 32 blocks ----
__global__ __launch_bounds__(256) void pool_kernel(const float* __restrict__ hn,
    float* __restrict__ feat){
  __shared__ float part[4][64];
  int b = blockIdx.x >> 3, dg = blockIdx.x & 7;
  int t = threadIdx.x, dl = t & 63, lq = t >> 6;
  const float* p = hn + (size_t)(b*256 + lq*64)*512 + dg*64 + dl;
  float s = 0.f;
#pragma unroll 4
  for (int i = 0; i < 64; ++i) s += p[(size_t)i*512];
  part[lq][dl] = s;
  __syncthreads();
  if (t < 64)
    feat[b*512 + dg*64 + t] =
        (part[0][t] + part[1][t] + part[2][t] + part[3][t]) * (1.f/256.f);
}

// ---- head: LN + fc1/relu + fc2; 4 blocks ----
__global__ __launch_bounds__(512) void head_kernel(const float* __restrict__ feat,
    const float* __restrict__ lnw, const float* __restrict__ lnb,
    const float* __restrict__ fc1w, const float* __restrict__ fc1b,
    const float* __restrict__ fc2w, const float* __restrict__ fc2b,
    float* __restrict__ out){
  __shared__ float sc[16];
  __shared__ float cbuf[512];
  __shared__ float rbuf[512];
  int b = blockIdx.x, t = threadIdx.x;
  float v = feat[b*512 + t];
  float s = v, ss = v*v;
  block_reduce2(s, ss, sc, 8);
  float mean = s * (1.f/512.f);
  float var = ss * (1.f/512.f) - mean*mean;
  float inv = rsqrtf(var + 1e-5f);
  cbuf[t] = (v - mean)*inv*lnw[t] + lnb[t];
  __syncthreads();
  float a = fc1b[t];
  const float* w1 = fc1w + (size_t)t*512;
  for (int i = 0; i < 512; i += 8){
    float4 w0 = *(const float4*)(w1 + i);
    float4 w4 = *(const float4*)(w1 + i + 4);
    float wf[8] = {w0.x,w0.y,w0.z,w0.w,w4.x,w4.y,w4.z,w4.w};
#pragma unroll
    for (int j = 0; j < 8; ++j) a = fmaf(cbuf[i + j], wf[j], a);
  }
  rbuf[t] = fmaxf(a, 0.f);
  __syncthreads();
  if (t < 10){
    float a2 = fc2b[t];
    const float* w2 = fc2w + (size_t)t*512;
    for (int i = 0; i < 512; ++i) a2 = fmaf(rbuf[i], w2[i], a2);
    out[b*10 + t] = a2;
  }
}

extern "C" void kernel_launch(void* const* d_in, const int* in_sizes, int n_in,
                              void* d_out, int out_size, void* d_ws, size_t ws_size,
                              hipStream_t stream) {
  (void)in_sizes; (void)n_in; (void)out_size; (void)ws_size;
  const float* x          = (const float*)d_in[0];
  const float* patch_w    = (const float*)d_in[1];
  const float* patch_b    = (const float*)d_in[2];
  const float* in_proj_w  = (const float*)d_in[3];
  const float* conv_w_f   = (const float*)d_in[4];
  const float* conv_b_f   = (const float*)d_in[5];
  const float* xproj_w_f  = (const float*)d_in[6];
  const float* dtproj_w_f = (const float*)d_in[7];
  const float* dtproj_b_f = (const float*)d_in[8];
  const float* A_log_f    = (const float*)d_in[9];
  const float* D_f        = (const float*)d_in[10];
  const float* conv_w_b   = (const float*)d_in[11];
  const float* conv_b_b   = (const float*)d_in[12];
  const float* xproj_w_b  = (const float*)d_in[13];
  const float* dtproj_w_b = (const float*)d_in[14];
  const float* dtproj_b_b = (const float*)d_in[15];
  const float* A_log_b    = (const float*)d_in[16];
  const float* D_b        = (const float*)d_in[17];
  const float* out_proj_w = (const float*)d_in[18];
  const float* norm_w     = (const float*)d_in[19];
  const float* norm_b     = (const float*)d_in[20];
  const float* normf_w    = (const float*)d_in[21];
  const float* normf_b    = (const float*)d_in[22];
  const float* ln_w       = (const float*)d_in[23];
  const float* ln_b       = (const float*)d_in[24];
  const float* fc1_w      = (const float*)d_in[25];
  const float* fc1_b      = (const float*)d_in[26];
  const float* fc2_w      = (const float*)d_in[27];
  const float* fc2_b      = (const float*)d_in[28];

  float* ws   = (float*)d_ws;
  float* hbuf = ws;                       // [0, 524288)
  float* xz   = ws + 524288;              // [524288, 2621440)
  u16*   uHi  = (u16*)(ws + 2621440);     // 2M u16
  u16*   uLo  = (u16*)(ws + 3670016);     // 2M u16
  float* xdbl = ws + 4718592;             // 131072
  float* ybuf = ws + 6946816;             // 2M
  float* hn   = ws + 9043968;             // 524288 ; xnHi/xnLo alias
  float* feat = ws + 11141120;            // 2048
  u16*   xnHi = (u16*)hn;
  u16*   xnLo = (u16*)(ws + 9306112);
  u16*   gHi  = (u16*)(ws + 2621440);     // reuse u region after scan
  u16*   gLo  = (u16*)(ws + 3145728);
  // ---- all-layer split-weight region (high part of ws) ----
  u16*   inHi4 = (u16*)(ws + 11145216);   // 4 x 1048576 u16
  u16*   inLo4 = (u16*)(ws + 13242368);
  u16*   outHi4= (u16*)(ws + 15339520);   // 4 x 524288 u16
  u16*   outLo4= (u16*)(ws + 16388096);
  u16*   xwHi4 = (u16*)(ws + 17436672);   // 4 x 131072 u16
  u16*   xwLo4 = (u16*)(ws + 17698816);
  u16*   dtwHi4= (u16*)(ws + 17960960);   // 4 x 65536 u16 (unused by scan now)
  u16*   dtwLo4= (u16*)(ws + 18092032);

  convert_w_all<<<dim3(1728, 4), 256, 0, stream>>>(
      in_proj_w, out_proj_w, xproj_w_f, xproj_w_b, dtproj_w_f, dtproj_w_b,
      inHi4, inLo4, outHi4, outLo4, xwHi4, xwLo4, dtwHi4, dtwLo4);
  patch_embed<<<256, 256, 0, stream>>>(x, patch_w, patch_b, hbuf);
  for (int i = 0; i < 4; ++i){
    prep_ln<<<1024, 256, 0, stream>>>(hbuf, norm_w, norm_b, i*512, xnHi, xnLo, xdbl);
    gemm_bf16<<<dim3(32, 16), 256, 0, stream>>>(
        xnHi, xnLo, 512, inHi4 + (size_t)i*1048576, inLo4 + (size_t)i*1048576,
        512, xz, 2048, 512, 0);
    conv_silu_split<<<512, 256, 0, stream>>>(
        xz, conv_w_f, conv_b_f, conv_w_b, conv_b_b, i*4096, i*1024, uHi, uLo);
    gemm_xproj_splitk<<<dim3(4, 32), 256, 0, stream>>>(
        uHi, uLo, xwHi4 + (size_t)i*131072, xwLo4 + (size_t)i*131072, xdbl);
    scan_coal<<<512, 256, 0, stream>>>(
        uHi, uLo, xdbl, dtproj_w_f, dtproj_w_b, dtproj_b_f, dtproj_b_b,
        A_log_f, A_log_b, D_f, D_b, i*32768, i*1024, i*16384, i*1024, ybuf);
    prep_gate<<<1024, 256, 0, stream>>>(ybuf, xz, gHi, gLo);
    gemm_bf16<<<dim3(8, 16), 256, 0, stream>>>(
        gHi, gLo, 1024, outHi4 + (size_t)i*524288, outLo4 + (size_t)i*524288,
        1024, hbuf, 512, 1024, 1);
  }
  ln_kernel<<<1024, 256, 0, stream>>>(hbuf, normf_w, normf_b, hn);
  pool_kernel<<<32, 256, 0, stream>>>(hn, feat);
  head_kernel<<<4, 512, 0, stream>>>(feat, ln_w, ln_b, fc1_w, fc1_b, fc2_w, fc2_b,
                                     (float*)d_out);
}